// Round 8
// baseline (1535.663 us; speedup 1.0000x reference)
//
#include <hip/hip_runtime.h>
#include <math.h>

#define B_    4096
#define N_    3400
#define NP2_  3584          // N_ padded to 256
#define D1_   2048
#define D2_   1024
#define E_    10
#define NE_   (E_ * D2_)    // 10240 fused ensemble columns
#define C_    17
#define TOPK_ 20
#define TAU_  10.0f

typedef __bf16 bf16x8 __attribute__((ext_vector_type(8)));
typedef __bf16 bf16x4 __attribute__((ext_vector_type(4)));
typedef float  f32x4  __attribute__((ext_vector_type(4)));

#define MFMA_(a,b,c) __builtin_amdgcn_mfma_f32_16x16x32_bf16(a,b,c,0,0,0)

__device__ inline float wsum64(float v){
  #pragma unroll
  for (int m = 1; m < 64; m <<= 1) v += __shfl_xor(v, m);
  return v;
}

__device__ __forceinline__ void gload_lds16(const unsigned short* g, unsigned short* l){
  __builtin_amdgcn_global_load_lds(
      (const __attribute__((address_space(1))) void*)g,
      (__attribute__((address_space(3))) void*)l, 16, 0, 0);
}

// --- row 1/max(||x||,eps) for [R][D] ---
__global__ __launch_bounds__(256)
void rownorm_inv(const float* __restrict__ X, int D, float* __restrict__ rinv){
  int r = blockIdx.x, t = threadIdx.x;
  const float4* x4 = reinterpret_cast<const float4*>(X + (long)r * D);
  float ss = 0.f;
  for (int i = t; i < (D >> 2); i += 256){
    float4 v = x4[i];
    ss += v.x*v.x + v.y*v.y + v.z*v.z + v.w*v.w;
  }
  __shared__ float red[256];
  red[t] = ss; __syncthreads();
  for (int s = 128; s; s >>= 1){ if (t < s) red[t] += red[t + s]; __syncthreads(); }
  if (t == 0) rinv[r] = 1.f / fmaxf(sqrtf(red[0]), 1e-12f);
}

__global__ void zero_cnt(float* cnt){ if (threadIdx.x < C_) cnt[threadIdx.x] = 0.f; }

__global__ __launch_bounds__(256)
void labelprep(const float* __restrict__ labels, int* __restrict__ y, float* __restrict__ cnt){
  int n = blockIdx.x * 256 + threadIdx.x;
  if (n >= N_) return;
  int c = 0;
  #pragma unroll
  for (int cc = 0; cc < C_; ++cc) if (labels[n * C_ + cc] > 0.5f) c = cc;
  y[n] = c;
  atomicAdd(&cnt[c], 1.0f);
}

// fp32 -> (hi bf16, lo bf16 of exact residual), 4 elems/thread
__global__ __launch_bounds__(256)
void cvt_split(const float* __restrict__ src, unsigned short* __restrict__ hi,
               unsigned short* __restrict__ lo, long n4){
  long i = (long)blockIdx.x * 256 + threadIdx.x;
  if (i >= n4) return;
  float4 v = reinterpret_cast<const float4*>(src)[i];
  float f[4] = {v.x, v.y, v.z, v.w};
  bf16x4 h4, l4;
  #pragma unroll
  for (int j = 0; j < 4; ++j){
    __bf16 h = (__bf16)f[j];
    h4[j] = h;
    l4[j] = (__bf16)(f[j] - (float)h);
  }
  reinterpret_cast<bf16x4*>(hi)[i] = h4;
  reinterpret_cast<bf16x4*>(lo)[i] = l4;
}

// zero-fill pad rows [N_, NP2_) of two bf16 [NP2_][D1_] arrays (16B stores)
__global__ __launch_bounds__(256)
void fill_pad(unsigned short* __restrict__ a, unsigned short* __restrict__ b){
  int i = blockIdx.x * 256 + threadIdx.x;   // 16B units; total (NP2_-N_)*D1_/8 = 47104
  uint4 zz = make_uint4(0,0,0,0);
  reinterpret_cast<uint4*>(a + (long)N_ * D1_)[i] = zz;
  reinterpret_cast<uint4*>(b + (long)N_ * D1_)[i] = zz;
}

// Wbf[e][n][k] = bf16(alpha[e][k] * W[n][k]),  laid out [NE_][D1_]
__global__ __launch_bounds__(256)
void wfold(const float* __restrict__ W, const float* __restrict__ alpha,
           unsigned short* __restrict__ wbf){
  long i = (long)blockIdx.x * 256 + threadIdx.x;       // float4 units
  const long perE = (long)D2_ * D1_ / 4;               // 524288
  int e = (int)(i / perE);
  long r = i - (long)e * perE;
  int k4 = (int)(r & (D1_/4 - 1));
  float4 wv = reinterpret_cast<const float4*>(W)[r];
  float4 av = reinterpret_cast<const float4*>(alpha + (long)e * D1_)[k4];
  bf16x4 o;
  o[0] = (__bf16)(wv.x * av.x);
  o[1] = (__bf16)(wv.y * av.y);
  o[2] = (__bf16)(wv.z * av.z);
  o[3] = (__bf16)(wv.w * av.w);
  reinterpret_cast<bf16x4*>(wbf)[i] = o;
}

// ==================== 8-phase 256x256 BK=64 MFMA core ====================
// Fragment-linear LDS: frag-block (sub,ks) at ushort (sub*2+ks)*512; lane l
// owns bytes [l*16, l*16+16) of each 1024B block (0 bank conflicts, and
// matches gload_lds's uniform-base + lane*16B write pattern exactly).
// 8 waves (wm=w>>2, wn=w&3); per-wave C = 128x64; acc[8][4] f32x4.
// Per K-tile (BK=64, buf=kt&1), 4 phases, each ending in s_barrier:
//  ph0: ds_read A[i0..3] + B[j0..1] -> 16 MFMA q(0,0)
//  ph1: ds_read B[j2..3]            -> 16 MFMA q(0,1)
//  ph2: ds_read A[i4..7]            -> 16 MFMA q(1,1)
//  ph3: stage kt+2 -> buf (8 gload_lds16/wave), 16 MFMA q(1,0),
//       s_waitcnt vmcnt(8) (counted: retires kt+1's stages, keeps kt+2's in flight)
// WAR safety: stages into buf only after its last ds_read (ph2) retired + barrier.

#define CORE_DECLS \
  __shared__ unsigned short LA[2][16384]; \
  __shared__ unsigned short LB[2][16384]; \
  const int nbx = gridDim.x; \
  const int nb  = nbx * gridDim.y; \
  int bid = blockIdx.y * nbx + blockIdx.x; \
  int swz = (bid & 7) * (nb >> 3) + (bid >> 3); \
  const int n0 = (swz % nbx) * 256; \
  const int m0 = (swz / nbx) * 256; \
  const int t = threadIdx.x, lane = t & 63, w = t >> 6; \
  const int wm = w >> 2, wn = w & 3; \
  const int r15 = lane & 15, kb = lane >> 4; \
  const unsigned d00 = (unsigned)(w*2)*512, d01 = (unsigned)(w*2+1)*512; \
  const unsigned d10 = (unsigned)((8+w)*2)*512, d11 = (unsigned)((8+w)*2+1)*512; \
  const unsigned raB = (unsigned)(wm*8)*1024 + (unsigned)lane*8; \
  const unsigned rbB = (unsigned)(wn*4)*1024 + (unsigned)lane*8;

#define PH0(la, lb) \
  { _Pragma("unroll") \
    for (int i = 0; i < 4; ++i){ \
      ar[i][0] = *(const bf16x8*)&la[raB + (unsigned)(i*2  )*512]; \
      ar[i][1] = *(const bf16x8*)&la[raB + (unsigned)(i*2+1)*512]; } \
    _Pragma("unroll") \
    for (int j = 0; j < 2; ++j){ \
      br[j][0] = *(const bf16x8*)&lb[rbB + (unsigned)(j*2  )*512]; \
      br[j][1] = *(const bf16x8*)&lb[rbB + (unsigned)(j*2+1)*512]; } \
    __builtin_amdgcn_s_setprio(1); \
    _Pragma("unroll") \
    for (int i = 0; i < 4; ++i) \
      _Pragma("unroll") \
      for (int j = 0; j < 2; ++j){ \
        acc[i][j] = MFMA_(ar[i][0], br[j][0], acc[i][j]); \
        acc[i][j] = MFMA_(ar[i][1], br[j][1], acc[i][j]); } \
    __builtin_amdgcn_s_setprio(0); \
    __builtin_amdgcn_s_barrier(); }

#define PH1(lb) \
  { _Pragma("unroll") \
    for (int j = 2; j < 4; ++j){ \
      br[j][0] = *(const bf16x8*)&lb[rbB + (unsigned)(j*2  )*512]; \
      br[j][1] = *(const bf16x8*)&lb[rbB + (unsigned)(j*2+1)*512]; } \
    __builtin_amdgcn_s_setprio(1); \
    _Pragma("unroll") \
    for (int i = 0; i < 4; ++i) \
      _Pragma("unroll") \
      for (int j = 2; j < 4; ++j){ \
        acc[i][j] = MFMA_(ar[i][0], br[j][0], acc[i][j]); \
        acc[i][j] = MFMA_(ar[i][1], br[j][1], acc[i][j]); } \
    __builtin_amdgcn_s_setprio(0); \
    __builtin_amdgcn_s_barrier(); }

#define PH2(la) \
  { _Pragma("unroll") \
    for (int i = 0; i < 4; ++i){ \
      ar[i][0] = *(const bf16x8*)&la[raB + (unsigned)((4+i)*2  )*512]; \
      ar[i][1] = *(const bf16x8*)&la[raB + (unsigned)((4+i)*2+1)*512]; } \
    __builtin_amdgcn_s_setprio(1); \
    _Pragma("unroll") \
    for (int i = 0; i < 4; ++i) \
      _Pragma("unroll") \
      for (int j = 2; j < 4; ++j){ \
        acc[4+i][j] = MFMA_(ar[i][0], br[j][0], acc[4+i][j]); \
        acc[4+i][j] = MFMA_(ar[i][1], br[j][1], acc[4+i][j]); } \
    __builtin_amdgcn_s_setprio(0); \
    __builtin_amdgcn_s_barrier(); }

#define PH3_MFMA \
  { __builtin_amdgcn_s_setprio(1); \
    _Pragma("unroll") \
    for (int i = 0; i < 4; ++i) \
      _Pragma("unroll") \
      for (int j = 0; j < 2; ++j){ \
        acc[4+i][j] = MFMA_(ar[i][0], br[j][0], acc[4+i][j]); \
        acc[4+i][j] = MFMA_(ar[i][1], br[j][1], acc[4+i][j]); } \
    __builtin_amdgcn_s_setprio(0); }

// Fused BatchEnsemble GEMM (8-phase). A [Mpad][D1_] bf16, Bw [NE_][D1_] bf16.
__global__ __launch_bounds__(512, 2)
void be8(const unsigned short* __restrict__ A,
         const unsigned short* __restrict__ Bw,
         const float* __restrict__ gamma,   // [NE_]
         const float* __restrict__ bias,    // [NE_]
         float* __restrict__ Out, long estride, int M)
{
  CORE_DECLS
  const unsigned short* a0p = A  + (long)(m0 +       w*16 + r15) * D1_ + kb*8;
  const unsigned short* a1p = A  + (long)(m0 + 128 + w*16 + r15) * D1_ + kb*8;
  const unsigned short* b0p = Bw + (long)(n0 +       w*16 + r15) * D1_ + kb*8;
  const unsigned short* b1p = Bw + (long)(n0 + 128 + w*16 + r15) * D1_ + kb*8;

#define STAGE_BE(buf, kt) do{ const int ko = (kt)*64; \
    gload_lds16(a0p+ko,    &LA[buf][d00]); gload_lds16(a0p+ko+32, &LA[buf][d01]); \
    gload_lds16(a1p+ko,    &LA[buf][d10]); gload_lds16(a1p+ko+32, &LA[buf][d11]); \
    gload_lds16(b0p+ko,    &LB[buf][d00]); gload_lds16(b0p+ko+32, &LB[buf][d01]); \
    gload_lds16(b1p+ko,    &LB[buf][d10]); gload_lds16(b1p+ko+32, &LB[buf][d11]); }while(0)

  f32x4 acc[8][4];
  #pragma unroll
  for (int i = 0; i < 8; ++i)
    #pragma unroll
    for (int j = 0; j < 4; ++j)
      acc[i][j] = (f32x4){0.f, 0.f, 0.f, 0.f};

  STAGE_BE(0, 0);
  STAGE_BE(1, 1);
  asm volatile("s_waitcnt vmcnt(8)" ::: "memory");
  __builtin_amdgcn_sched_barrier(0);
  __builtin_amdgcn_s_barrier();

  for (int kt = 0; kt < 32; ++kt){
    const int cb = kt & 1;
    const unsigned short* la = &LA[cb][0];
    const unsigned short* lb = &LB[cb][0];
    bf16x8 ar[4][2], br[4][2];
    PH0(la, lb)
    PH1(lb)
    PH2(la)
    if (kt < 30){
      STAGE_BE(cb, kt + 2);
      PH3_MFMA
      asm volatile("s_waitcnt vmcnt(8)" ::: "memory");
    } else {
      PH3_MFMA
      asm volatile("s_waitcnt vmcnt(0)" ::: "memory");
    }
    __builtin_amdgcn_sched_barrier(0);
    __builtin_amdgcn_s_barrier();
  }
#undef STAGE_BE

  const int mrow = m0 + wm*128 + (lane >> 4)*4;
  const int nc0  = n0 + wn*64 + (lane & 15);
  #pragma unroll
  for (int j = 0; j < 4; ++j){
    int n = nc0 + j*16;                // fused column in [0, NE_)
    int e = n >> 10, nc = n & 1023;
    float g = gamma[n], o = bias[n];
    float* op = Out + (long)e * estride;
    #pragma unroll
    for (int i = 0; i < 8; ++i){
      #pragma unroll
      for (int r = 0; r < 4; ++r){
        int m = mrow + i*16 + r;
        if (m < M) op[(long)m * D2_ + nc] = acc[i][j][r] * g + o;
      }
    }
  }
}

// scores[m][n] = zinv[m]*sinv[n]*(Z·S), split-bf16 3-term as flat 96 K-tiles:
// seg0 (zh,sh), seg1 (zh,sl), seg2 (zl,sh); 8-phase core.
__global__ __launch_bounds__(512, 2)
void sc8(const unsigned short* __restrict__ zh, const unsigned short* __restrict__ zl,
         const unsigned short* __restrict__ sh, const unsigned short* __restrict__ sl,
         const float* __restrict__ zinv, const float* __restrict__ sinv,
         float* __restrict__ Out)
{
  CORE_DECLS
  const long ao0 = (long)(m0 +       w*16 + r15) * D1_ + kb*8;
  const long ao1 = (long)(m0 + 128 + w*16 + r15) * D1_ + kb*8;
  const long bo0 = (long)(n0 +       w*16 + r15) * D1_ + kb*8;
  const long bo1 = (long)(n0 + 128 + w*16 + r15) * D1_ + kb*8;

#define STAGE_SC(buf, kt) do{ const int sg = (kt) >> 5; const int ko = ((kt) & 31)*64; \
    const unsigned short* ap = (sg == 2) ? zl : zh; \
    const unsigned short* bp = (sg == 1) ? sl : sh; \
    gload_lds16(ap+ao0+ko,    &LA[buf][d00]); gload_lds16(ap+ao0+ko+32, &LA[buf][d01]); \
    gload_lds16(ap+ao1+ko,    &LA[buf][d10]); gload_lds16(ap+ao1+ko+32, &LA[buf][d11]); \
    gload_lds16(bp+bo0+ko,    &LB[buf][d00]); gload_lds16(bp+bo0+ko+32, &LB[buf][d01]); \
    gload_lds16(bp+bo1+ko,    &LB[buf][d10]); gload_lds16(bp+bo1+ko+32, &LB[buf][d11]); }while(0)

  f32x4 acc[8][4];
  #pragma unroll
  for (int i = 0; i < 8; ++i)
    #pragma unroll
    for (int j = 0; j < 4; ++j)
      acc[i][j] = (f32x4){0.f, 0.f, 0.f, 0.f};

  STAGE_SC(0, 0);
  STAGE_SC(1, 1);
  asm volatile("s_waitcnt vmcnt(8)" ::: "memory");
  __builtin_amdgcn_sched_barrier(0);
  __builtin_amdgcn_s_barrier();

  for (int kt = 0; kt < 96; ++kt){
    const int cb = kt & 1;
    const unsigned short* la = &LA[cb][0];
    const unsigned short* lb = &LB[cb][0];
    bf16x8 ar[4][2], br[4][2];
    PH0(la, lb)
    PH1(lb)
    PH2(la)
    if (kt < 94){
      STAGE_SC(cb, kt + 2);
      PH3_MFMA
      asm volatile("s_waitcnt vmcnt(8)" ::: "memory");
    } else {
      PH3_MFMA
      asm volatile("s_waitcnt vmcnt(0)" ::: "memory");
    }
    __builtin_amdgcn_sched_barrier(0);
    __builtin_amdgcn_s_barrier();
  }
#undef STAGE_SC

  const int mrow = m0 + wm*128 + (lane >> 4)*4;
  const int nc0  = n0 + wn*64 + (lane & 15);
  #pragma unroll
  for (int j = 0; j < 4; ++j){
    int n = nc0 + j*16;
    if (n >= N_) continue;
    float si = sinv[n];
    #pragma unroll
    for (int i = 0; i < 8; ++i){
      #pragma unroll
      for (int r = 0; r < 4; ++r){
        int m = mrow + i*16 + r;
        Out[(long)m * N_ + n] = acc[i][j][r] * zinv[m] * si;
      }
    }
  }
}

// register-resident top-20 (value desc, tie -> lower index) per row of scores[B_][N_]
__global__ __launch_bounds__(256)
void topk20(const float* __restrict__ scores, int* __restrict__ idx){
  const int b = blockIdx.x, t = threadIdx.x;
  const int l = t & 63, wid = t >> 6;
  const float* row = scores + (long)b * N_;
  float v[14];
  #pragma unroll
  for (int j = 0; j < 14; ++j){
    int i = t + j * 256;
    v[j] = (i < N_) ? row[i] : -3.0e38f;
  }
  __shared__ float wv[4];
  __shared__ int   wi[4];
  for (int it = 0; it < TOPK_; ++it){
    float bv = -3.0e38f; int bj = 0;
    #pragma unroll
    for (int j = 0; j < 14; ++j)
      if (v[j] > bv){ bv = v[j]; bj = j; }
    int bi = t + bj * 256;
    #pragma unroll
    for (int m = 1; m < 64; m <<= 1){
      float ov = __shfl_xor(bv, m);
      int   oi = __shfl_xor(bi, m);
      if (ov > bv || (ov == bv && oi < bi)){ bv = ov; bi = oi; }
    }
    if (l == 0){ wv[wid] = bv; wi[wid] = bi; }
    __syncthreads();
    float gv = wv[0]; int gi = wi[0];
    #pragma unroll
    for (int k = 1; k < 4; ++k){
      float ov = wv[k]; int oi = wi[k];
      if (ov > gv || (ov == gv && oi < gi)){ gv = ov; gi = oi; }
    }
    if (t == 0) idx[b * TOPK_ + it] = gi;
    const int ot = gi & 255, oj = gi >> 8;
    #pragma unroll
    for (int j = 0; j < 14; ++j)
      if (t == ot && j == oj) v[j] = -3.0e38f;
    __syncthreads();
  }
}

__global__ __launch_bounds__(256)
void centroid_part(const float* __restrict__ mlps, const int* __restrict__ y,
                   const float* __restrict__ cnt, float* __restrict__ part){
  __shared__ float acc[C_ * 256];
  __shared__ float winv[C_];
  const int t  = threadIdx.x;
  const int ob = blockIdx.x * 256;
  const int e  = blockIdx.y;
  const int s  = blockIdx.z;
  #pragma unroll
  for (int c = 0; c < C_; ++c) acc[c * 256 + t] = 0.f;
  if (t < C_) winv[t] = 1.f / (cnt[t] + 1e-12f);
  __syncthreads();
  const int n0 = s * 425, n1 = n0 + 425;
  for (int n = n0; n < n1; ++n){
    int c = y[n];
    float v = mlps[((long)e * N_ + n) * D2_ + ob + t];
    acc[c * 256 + t] += winv[c] * v;
  }
  #pragma unroll
  for (int c = 0; c < C_; ++c)
    part[(((long)s * E_ + e) * C_ + c) * D2_ + ob + t] = acc[c * 256 + t];
}

__global__ __launch_bounds__(256)
void centroid_reduce(const float* __restrict__ part, float* __restrict__ cent){
  int i = blockIdx.x * 256 + threadIdx.x;
  if (i >= E_ * C_ * D2_) return;
  float s = 0.f;
  #pragma unroll
  for (int k = 0; k < 8; ++k) s += part[(long)k * E_ * C_ * D2_ + i];
  cent[i] = s;
}

__global__ __launch_bounds__(256)
void rownorm_inplace(float* __restrict__ X, int D){
  int r = blockIdx.x, t = threadIdx.x;
  float4* x4 = reinterpret_cast<float4*>(X + (long)r * D);
  float ss = 0.f;
  for (int i = t; i < (D >> 2); i += 256){
    float4 v = x4[i];
    ss += v.x*v.x + v.y*v.y + v.z*v.z + v.w*v.w;
  }
  __shared__ float red[256];
  red[t] = ss; __syncthreads();
  for (int s2 = 128; s2; s2 >>= 1){ if (t < s2) red[t] += red[t + s2]; __syncthreads(); }
  float rinv = 1.f / fmaxf(sqrtf(red[0]), 1e-12f);
  for (int i = t; i < (D >> 2); i += 256){
    float4 v = x4[i];
    v.x *= rinv; v.y *= rinv; v.z *= rinv; v.w *= rinv;
    x4[i] = v;
  }
}

// per (e,row): 17 cosine dots with cn; mode 1 -> softmax, mode 0 -> TAU*cos
__global__ __launch_bounds__(256)
void ens_dot(const float* __restrict__ mlp, const float* __restrict__ cn,
             float* __restrict__ out, int mlp_rows, int out_M, int out_rowoff, int mode){
  const int wv = threadIdx.x >> 6, l = threadIdx.x & 63;
  const int row = blockIdx.x * 4 + wv, e = blockIdx.y;
  if (row >= mlp_rows) return;
  const float4* r4 = reinterpret_cast<const float4*>(mlp + ((long)e * mlp_rows + row) * D2_);
  float4 r[4];
  #pragma unroll
  for (int j = 0; j < 4; ++j) r[j] = r4[j * 64 + l];
  float ss = 0.f;
  #pragma unroll
  for (int j = 0; j < 4; ++j) ss += r[j].x*r[j].x + r[j].y*r[j].y + r[j].z*r[j].z + r[j].w*r[j].w;
  ss = wsum64(ss);
  float rinv = 1.f / fmaxf(sqrtf(ss), 1e-12f);
  float tv[C_];
  #pragma unroll
  for (int c = 0; c < C_; ++c){
    const float4* c4 = reinterpret_cast<const float4*>(cn + ((long)e * C_ + c) * D2_);
    float p = 0.f;
    #pragma unroll
    for (int j = 0; j < 4; ++j){
      float4 cv = c4[j * 64 + l];
      p += r[j].x*cv.x + r[j].y*cv.y + r[j].z*cv.z + r[j].w*cv.w;
    }
    tv[c] = wsum64(p) * rinv * TAU_;
  }
  long obase = ((long)e * out_M + out_rowoff + row) * C_;
  if (mode == 0){
    if (l == 0){
      #pragma unroll
      for (int c = 0; c < C_; ++c) out[obase + c] = tv[c];
    }
  } else {
    float m = tv[0];
    #pragma unroll
    for (int c = 1; c < C_; ++c) m = fmaxf(m, tv[c]);
    float p[C_]; float sum = 0.f;
    #pragma unroll
    for (int c = 0; c < C_; ++c){ p[c] = expf(tv[c] - m); sum += p[c]; }
    float is = 1.f / sum;
    if (l == 0){
      #pragma unroll
      for (int c = 0; c < C_; ++c) out[obase + c] = p[c] * is;
    }
  }
}

__global__ __launch_bounds__(256)
void outputs_k(const float* __restrict__ soft, const int* __restrict__ idx, float* __restrict__ out){
  const int lane = threadIdx.x & 63;
  const int b = blockIdx.x * 4 + (threadIdx.x >> 6);
  const int* id = idx + b * TOPK_;
  float o = 0.f;
  for (int e = 0; e < E_; ++e){
    float S = 0.f;
    const float* se = soft + (long)e * N_ * C_;
    #pragma unroll
    for (int k = 0; k < TOPK_; ++k){
      int n = id[k];
      if (lane < C_) S += se[(long)n * C_ + lane];
    }
    float tot = wsum64(S);
    o += S / (tot + 1e-12f);
  }
  if (lane < C_) out[(long)b * C_ + lane] = o * (1.f / E_);
}

extern "C" void kernel_launch(void* const* d_in, const int* in_sizes, int n_in,
                              void* d_out, int out_size, void* d_ws, size_t ws_size,
                              hipStream_t stream){
  const float* z        = (const float*)d_in[0];
  const float* supports = (const float*)d_in[1];
  const float* labels   = (const float*)d_in[2];
  const float* weight   = (const float*)d_in[3];
  const float* alpha    = (const float*)d_in[4];
  const float* gamma    = (const float*)d_in[5];
  const float* bias     = (const float*)d_in[6];
  float* out = (float*)d_out;

  char* w = (char*)d_ws;
  size_t off = 0;
  auto alloc = [&](size_t bytes)->char*{
    char* p = w + off;
    off = (off + bytes + 255) & ~(size_t)255;
    return p;
  };
  auto rup = [](size_t b)->size_t{ return (b + 255) & ~(size_t)255; };

  // ---- permanent region (~83 MB) ----
  float* zinv   = (float*)alloc((size_t)B_ * 4);
  float* sinv   = (float*)alloc((size_t)N_ * 4);
  float* cnt    = (float*)alloc((size_t)C_ * 4);
  int*   y      = (int*)  alloc((size_t)N_ * 4);
  int*   idx    = (int*)  alloc((size_t)B_ * TOPK_ * 4);
  unsigned short* zh  = (unsigned short*)alloc((size_t)B_   * D1_ * 2);
  unsigned short* sh  = (unsigned short*)alloc((size_t)NP2_ * D1_ * 2);
  unsigned short* wbf = (unsigned short*)alloc((size_t)NE_ * D1_ * 2);
  float* cent = (float*)alloc((size_t)E_ * C_ * D2_ * 4);
  float* part = (float*)alloc((size_t)8 * E_ * C_ * D2_ * 4);
  float* soft = (float*)alloc((size_t)E_ * N_ * C_ * 4);

  // ---- overlay region (≈139 MB): scores|zl|sl -> mlps -> mlpz ----
  const size_t scores_b = (size_t)B_ * N_ * 4;
  const size_t zl_b     = (size_t)B_   * D1_ * 2;
  const size_t sl_b     = (size_t)NP2_ * D1_ * 2;
  const size_t mlps_b   = (size_t)E_ * N_ * D2_ * 4;
  size_t ph1 = rup(scores_b) + rup(zl_b) + rup(sl_b);
  char* overlay = alloc(ph1 > mlps_b ? ph1 : mlps_b);
  float*          scores = (float*)overlay;
  unsigned short* zl     = (unsigned short*)(overlay + rup(scores_b));
  unsigned short* sl     = (unsigned short*)(overlay + rup(scores_b) + rup(zl_b));
  float*          mlps   = (float*)overlay;          // after topk20
  float*          mlpz   = (float*)overlay;          // after ens_dot(soft)
  (void)ws_size; (void)in_sizes; (void)n_in; (void)out_size;

  // row norms + label prep
  rownorm_inv<<<B_, 256, 0, stream>>>(z, D1_, zinv);
  rownorm_inv<<<N_, 256, 0, stream>>>(supports, D1_, sinv);
  zero_cnt<<<1, 32, 0, stream>>>(cnt);
  labelprep<<<(N_ + 255) / 256, 256, 0, stream>>>(labels, y, cnt);

  // bf16 precompute: hi/lo splits, pad to 3584, folded W
  cvt_split<<<(B_ * D1_ / 4 + 255) / 256, 256, 0, stream>>>(z, zh, zl, (long)B_ * D1_ / 4);
  cvt_split<<<(N_ * D1_ / 4 + 255) / 256, 256, 0, stream>>>(supports, sh, sl, (long)N_ * D1_ / 4);
  fill_pad<<<(NP2_ - N_) * D1_ / 8 / 256, 256, 0, stream>>>(sh, sl);
  wfold<<<(int)((long)NE_ * D1_ / 4 / 256), 256, 0, stream>>>(weight, alpha, wbf);

  // cosine scores (split-bf16 3-term, 8-phase) + top-20
  sc8<<<dim3(NP2_ / 256, B_ / 256, 1), 512, 0, stream>>>(
      zh, zl, sh, sl, zinv, sinv, scores);
  topk20<<<B_, 256, 0, stream>>>(scores, idx);
  // (scores, zl, sl dead from here)

  // mlp_s: fused GEMM over N' = E*D2 columns (8-phase)
  be8<<<dim3(NE_ / 256, NP2_ / 256, 1), 512, 0, stream>>>(
      sh, wbf, gamma, bias, mlps, (long)N_ * D2_, N_);

  // centroids, then L2-normalize rows
  centroid_part<<<dim3(D2_ / 256, E_, 8), 256, 0, stream>>>(mlps, y, cnt, part);
  centroid_reduce<<<(E_ * C_ * D2_ + 255) / 256, 256, 0, stream>>>(part, cent);
  rownorm_inplace<<<E_ * C_, 256, 0, stream>>>(cent, D2_);

  // soft = softmax(TAU * cos(mlp_s, cent))
  ens_dot<<<dim3((N_ + 3) / 4, E_), 256, 0, stream>>>(mlps, cent, soft, N_, N_, 0, 1);

  // outputs
  outputs_k<<<B_ / 4, 256, 0, stream>>>(soft, idx, out);
  // (mlps dead from here; mlpz reuses its space)

  // logits, 2 chunks of 2048 z rows
  float* logits = out + (size_t)B_ * C_;
  for (int ch = 0; ch < 2; ++ch){
    be8<<<dim3(NE_ / 256, 2048 / 256, 1), 512, 0, stream>>>(
        zh + (size_t)ch * 2048 * D1_, wbf, gamma, bias, mlpz, (long)2048 * D2_, 2048);
    ens_dot<<<dim3(2048 / 4, E_), 256, 0, stream>>>(mlpz, cent, logits, 2048, B_, ch * 2048, 0);
  }
}

// Round 9
// 1357.505 us; speedup vs baseline: 1.1312x; 1.1312x over previous
//
#include <hip/hip_runtime.h>
#include <math.h>

#define B_    4096
#define N_    3400
#define NP_   3456          // N_ padded to 128 (scores tile grid)
#define D1_   2048
#define D2_   1024
#define E_    10
#define NE_   (E_ * D2_)    // 10240 fused ensemble columns
#define NDOT_ 256           // extra dot columns (170 used)
#define NEX_  (NE_ + NDOT_) // 10496
#define ZOFF_ 3456          // z rows start in SZ
#define MR_   7680          // SZ total rows (3456 S + 4096 z + 128 pad)
#define EC_   170           // E_*C_
#define C_    17
#define TOPK_ 20
#define TAU_  10.0f

typedef __bf16 bf16x8 __attribute__((ext_vector_type(8)));
typedef __bf16 bf16x4 __attribute__((ext_vector_type(4)));
typedef float  f32x4  __attribute__((ext_vector_type(4)));

__device__ inline float wsum64(float v){
  #pragma unroll
  for (int m = 1; m < 64; m <<= 1) v += __shfl_xor(v, m);
  return v;
}

__device__ __forceinline__ void gload_lds16(const unsigned short* g, unsigned short* l){
  __builtin_amdgcn_global_load_lds(
      (const __attribute__((address_space(1))) void*)g,
      (__attribute__((address_space(3))) void*)l, 16, 0, 0);
}

// --- row 1/max(||x||,eps) for [R][D] ---
__global__ __launch_bounds__(256)
void rownorm_inv(const float* __restrict__ X, int D, float* __restrict__ rinv){
  int r = blockIdx.x, t = threadIdx.x;
  const float4* x4 = reinterpret_cast<const float4*>(X + (long)r * D);
  float ss = 0.f;
  for (int i = t; i < (D >> 2); i += 256){
    float4 v = x4[i];
    ss += v.x*v.x + v.y*v.y + v.z*v.z + v.w*v.w;
  }
  __shared__ float red[256];
  red[t] = ss; __syncthreads();
  for (int s = 128; s; s >>= 1){ if (t < s) red[t] += red[t + s]; __syncthreads(); }
  if (t == 0) rinv[r] = 1.f / fmaxf(sqrtf(red[0]), 1e-12f);
}

__global__ void zero_cnt(float* cnt){ if (threadIdx.x < C_) cnt[threadIdx.x] = 0.f; }

__global__ __launch_bounds__(256)
void zfill(uint4* __restrict__ p, long n){
  long i = (long)blockIdx.x * 256 + threadIdx.x;
  if (i < n) p[i] = make_uint4(0,0,0,0);
}

__global__ __launch_bounds__(256)
void labelprep(const float* __restrict__ labels, int* __restrict__ y, float* __restrict__ cnt){
  int n = blockIdx.x * 256 + threadIdx.x;
  if (n >= N_) return;
  int c = 0;
  #pragma unroll
  for (int cc = 0; cc < C_; ++cc) if (labels[n * C_ + cc] > 0.5f) c = cc;
  y[n] = c;
  atomicAdd(&cnt[c], 1.0f);
}

// fp32 -> (hi bf16, lo bf16 of exact residual)
__global__ __launch_bounds__(256)
void cvt_split(const float* __restrict__ src, unsigned short* __restrict__ hi,
               unsigned short* __restrict__ lo, long n4){
  long i = (long)blockIdx.x * 256 + threadIdx.x;
  if (i >= n4) return;
  float4 v = reinterpret_cast<const float4*>(src)[i];
  float f[4] = {v.x, v.y, v.z, v.w};
  bf16x4 h4, l4;
  #pragma unroll
  for (int j = 0; j < 4; ++j){
    __bf16 h = (__bf16)f[j];
    h4[j] = h;
    l4[j] = (__bf16)(f[j] - (float)h);
  }
  reinterpret_cast<bf16x4*>(hi)[i] = h4;
  reinterpret_cast<bf16x4*>(lo)[i] = l4;
}

// Wbf[e][n][k] = bf16(alpha[e][k] * W[n][k]),  laid out [NE_][D1_]
__global__ __launch_bounds__(256)
void wfold(const float* __restrict__ W, const float* __restrict__ alpha,
           unsigned short* __restrict__ wbf){
  long i = (long)blockIdx.x * 256 + threadIdx.x;       // float4 units
  const long perE = (long)D2_ * D1_ / 4;
  int e = (int)(i / perE);
  long r = i - (long)e * perE;
  int k4 = (int)(r & (D1_/4 - 1));
  float4 wv = reinterpret_cast<const float4*>(W)[r];
  float4 av = reinterpret_cast<const float4*>(alpha + (long)e * D1_)[k4];
  bf16x4 o;
  o[0] = (__bf16)(wv.x * av.x);
  o[1] = (__bf16)(wv.y * av.y);
  o[2] = (__bf16)(wv.z * av.z);
  o[3] = (__bf16)(wv.w * av.w);
  reinterpret_cast<bf16x4*>(wbf)[i] = o;
}

// WT[k][d] = W[d][k]
__global__ __launch_bounds__(256)
void transposeW(const float* __restrict__ W, float* __restrict__ WT){
  __shared__ float tile[32][33];
  const int bx = blockIdx.x, by = blockIdx.y;
  const int tx = threadIdx.x & 31, ty = threadIdx.x >> 5;
  #pragma unroll
  for (int i = 0; i < 4; ++i)
    tile[ty + i*8][tx] = W[(long)(by*32 + ty + i*8) * D1_ + bx*32 + tx];
  __syncthreads();
  #pragma unroll
  for (int i = 0; i < 4; ++i)
    WT[(long)(bx*32 + ty + i*8) * D2_ + by*32 + tx] = tile[tx][ty + i*8];
}

// partial P: part[s][c][k] = sum_{n in slice s, y[n]=c} S[n,k]/(cnt_c+eps)
__global__ __launch_bounds__(256)
void pbuild(const float* __restrict__ S, const int* __restrict__ y,
            const float* __restrict__ cnt, float* __restrict__ part){
  __shared__ float acc[C_ * 256];
  __shared__ float winv[C_];
  const int t = threadIdx.x, kb = blockIdx.x * 256, s = blockIdx.y;
  #pragma unroll
  for (int c = 0; c < C_; ++c) acc[c * 256 + t] = 0.f;
  if (t < C_) winv[t] = 1.f / (cnt[t] + 1e-12f);
  __syncthreads();
  const int n0 = s * 425, n1 = n0 + 425;
  for (int n = n0; n < n1; ++n){
    int c = y[n];
    acc[c * 256 + t] += winv[c] * S[(long)n * D1_ + kb + t];
  }
  #pragma unroll
  for (int c = 0; c < C_; ++c)
    part[((long)s * C_ + c) * D1_ + kb + t] = acc[c * 256 + t];
}

__global__ __launch_bounds__(256)
void preduce(const float* __restrict__ part, float* __restrict__ P){
  int i = blockIdx.x * 256 + threadIdx.x;
  if (i >= C_ * D1_) return;
  float s = 0.f;
  #pragma unroll
  for (int k = 0; k < 8; ++k) s += part[(long)k * C_ * D1_ + i];
  P[i] = s;
}

// A2[ec][k] = P[c][k]*alpha[e][k]
__global__ __launch_bounds__(256)
void a2build(const float* __restrict__ P, const float* __restrict__ alpha,
             float* __restrict__ A2){
  int i = blockIdx.x * 256 + threadIdx.x;
  if (i >= EC_ * D1_) return;
  int ec = i >> 11, k = i & (D1_ - 1);
  int e = ec / C_, c = ec - e * C_;
  A2[i] = P[c * D1_ + k] * alpha[(long)e * D1_ + k];
}

// cent[ec][d] = gamma[e][d]*pre[ec][d] + bias[e][d]*s_c
__global__ __launch_bounds__(256)
void centscale(const float* __restrict__ pre, const float* __restrict__ gamma,
               const float* __restrict__ bias, const float* __restrict__ cnt,
               float* __restrict__ cent){
  int i = blockIdx.x * 256 + threadIdx.x;
  if (i >= EC_ * D2_) return;
  int ec = i >> 10, d = i & (D2_ - 1);
  int e = ec / C_, c = ec - e * C_;
  float sc = cnt[c] / (cnt[c] + 1e-12f);
  cent[i] = gamma[(long)e * D2_ + d] * pre[i] + bias[(long)e * D2_ + d] * sc;
}

__global__ __launch_bounds__(256)
void rownorm_inplace(float* __restrict__ X, int D){
  int r = blockIdx.x, t = threadIdx.x;
  float4* x4 = reinterpret_cast<float4*>(X + (long)r * D);
  float ss = 0.f;
  for (int i = t; i < (D >> 2); i += 256){
    float4 v = x4[i];
    ss += v.x*v.x + v.y*v.y + v.z*v.z + v.w*v.w;
  }
  __shared__ float red[256];
  red[t] = ss; __syncthreads();
  for (int s2 = 128; s2; s2 >>= 1){ if (t < s2) red[t] += red[t + s2]; __syncthreads(); }
  float rinv = 1.f / fmaxf(sqrtf(red[0]), 1e-12f);
  for (int i = t; i < (D >> 2); i += 256){
    float4 v = x4[i];
    v.x *= rinv; v.y *= rinv; v.z *= rinv; v.w *= rinv;
    x4[i] = v;
  }
}

// gcn[ec][d] = gamma[e][d]*cn[ec][d]   (cn = normalized cent)
__global__ __launch_bounds__(256)
void gcnbuild(const float* __restrict__ cn, const float* __restrict__ gamma,
              float* __restrict__ gcn){
  int i = blockIdx.x * 256 + threadIdx.x;
  if (i >= EC_ * D2_) return;
  int ec = i >> 10, d = i & (D2_ - 1);
  int e = ec / C_;
  gcn[i] = gamma[(long)e * D2_ + d] * cn[i];
}

// wbf[NE_+ec][k] = bf16(alpha[e][k]*H[ec][k])
__global__ __launch_bounds__(256)
void gbuild(const float* __restrict__ H, const float* __restrict__ alpha,
            unsigned short* __restrict__ wbf){
  int i = blockIdx.x * 256 + threadIdx.x;
  if (i >= EC_ * D1_) return;
  int ec = i >> 11, k = i & (D1_ - 1);
  int e = ec / C_;
  float v = alpha[(long)e * D1_ + k] * H[i];
  __bf16 b = (__bf16)v;
  wbf[(long)(NE_ + ec) * D1_ + k] = *(unsigned short*)&b;
}

// bconst[ec] = sum_d bias[e][d]*cn[ec][d]
__global__ __launch_bounds__(256)
void bconst_build(const float* __restrict__ bias, const float* __restrict__ cn,
                  float* __restrict__ bconst){
  const int wv = threadIdx.x >> 6, l = threadIdx.x & 63;
  const int ec = blockIdx.x * 4 + wv;
  if (ec >= EC_) return;
  const int e = ec / C_;
  float s = 0.f;
  #pragma unroll
  for (int j = 0; j < 16; ++j){
    int d = l + j * 64;
    s += bias[(long)e * D2_ + d] * cn[(long)ec * D2_ + d];
  }
  s = wsum64(s);
  if (l == 0) bconst[ec] = s;
}

// fp32 vector GEMM (small problems): Out[m][n] = rs*cs*( sum_k A[m,k]*B[n,k] )
__global__ __launch_bounds__(256)
void gemm64(const float* __restrict__ A, int lda,
            const float* __restrict__ Bm, int ldb,
            float* __restrict__ Out, int ldo,
            int M, int N, int K)
{
  __shared__ float As[16][68];
  __shared__ float Bs[16][68];
  const int m0 = blockIdx.y * 64, n0 = blockIdx.x * 64;
  const int t  = threadIdx.x;
  const int lr = t >> 2;
  const int lk = (t & 3) << 2;
  const int ty4 = (t >> 4) << 2;
  const int tx4 = (t & 15) << 2;
  const bool aok = (m0 + lr) < M;
  const bool bok = (n0 + lr) < N;
  const float* ap = A  + (long)(m0 + lr) * lda + lk;
  const float* bp = Bm + (long)(n0 + lr) * ldb + lk;
  float acc[4][4] = {{0.f}};
  for (int k0 = 0; k0 < K; k0 += 16){
    float4 av = make_float4(0,0,0,0), bv = make_float4(0,0,0,0);
    if (aok) av = *reinterpret_cast<const float4*>(ap + k0);
    if (bok) bv = *reinterpret_cast<const float4*>(bp + k0);
    As[lk+0][lr] = av.x; As[lk+1][lr] = av.y; As[lk+2][lr] = av.z; As[lk+3][lr] = av.w;
    Bs[lk+0][lr] = bv.x; Bs[lk+1][lr] = bv.y; Bs[lk+2][lr] = bv.z; Bs[lk+3][lr] = bv.w;
    __syncthreads();
    #pragma unroll
    for (int kk = 0; kk < 16; ++kk){
      float4 a = *reinterpret_cast<const float4*>(&As[kk][ty4]);
      float4 b = *reinterpret_cast<const float4*>(&Bs[kk][tx4]);
      float aa[4] = {a.x, a.y, a.z, a.w};
      float bb[4] = {b.x, b.y, b.z, b.w};
      #pragma unroll
      for (int i = 0; i < 4; ++i)
        #pragma unroll
        for (int j = 0; j < 4; ++j)
          acc[i][j] += aa[i] * bb[j];
    }
    __syncthreads();
  }
  #pragma unroll
  for (int i = 0; i < 4; ++i){
    int m = m0 + ty4 + i;
    if (m >= M) continue;
    #pragma unroll
    for (int j = 0; j < 4; ++j){
      int n = n0 + tx4 + j;
      if (n >= N) continue;
      Out[(long)m * ldo + n] = acc[i][j];
    }
  }
}

// scores[m][n] = zinv[m]*sinv[n]*(Z·S) via split-bf16 3-term MFMA (R7 known-good)
__global__ __launch_bounds__(256)
void mfma_scores2(const unsigned short* __restrict__ zh, const unsigned short* __restrict__ zl,
                  const unsigned short* __restrict__ sh, const unsigned short* __restrict__ sl,
                  const float* __restrict__ zinv, const float* __restrict__ sinv,
                  float* __restrict__ Out)
{
  __shared__ unsigned short Ah[128 * 32];
  __shared__ unsigned short Al[128 * 32];
  __shared__ unsigned short Bh[128 * 32];
  __shared__ unsigned short Bl[128 * 32];
  const int n0 = blockIdx.x * 128;
  const int m0 = blockIdx.y * 128;
  const int t  = threadIdx.x;
  const int lane = t & 63;
  const int w  = t >> 6;
  const int wr = w >> 1, wc = w & 1;
  const int r15 = lane & 15, kb = lane >> 4;

  const long arow0 = (long)(m0 + 32*w      + r15) * D1_ + kb * 8;
  const long arow1 = (long)(m0 + 32*w + 16 + r15) * D1_ + kb * 8;
  const long brow0 = (long)(n0 + 32*w      + r15) * D1_ + kb * 8;
  const long brow1 = (long)(n0 + 32*w + 16 + r15) * D1_ + kb * 8;
  const unsigned s0 = (2*w) * 512, s1 = (2*w+1) * 512;

  f32x4 acc[4][4];
  #pragma unroll
  for (int i = 0; i < 4; ++i)
    #pragma unroll
    for (int j = 0; j < 4; ++j)
      acc[i][j] = (f32x4){0.f, 0.f, 0.f, 0.f};

  for (int k0 = 0; k0 < D1_; k0 += 32){
    __syncthreads();
    gload_lds16(zh + arow0 + k0, &Ah[s0]);
    gload_lds16(zh + arow1 + k0, &Ah[s1]);
    gload_lds16(zl + arow0 + k0, &Al[s0]);
    gload_lds16(zl + arow1 + k0, &Al[s1]);
    gload_lds16(sh + brow0 + k0, &Bh[s0]);
    gload_lds16(sh + brow1 + k0, &Bh[s1]);
    gload_lds16(sl + brow0 + k0, &Bl[s0]);
    gload_lds16(sl + brow1 + k0, &Bl[s1]);
    __syncthreads();

    bf16x8 afh[4], bfh[4];
    #pragma unroll
    for (int i = 0; i < 4; ++i)
      afh[i] = *reinterpret_cast<const bf16x8*>(&Ah[(wr*4 + i) * 512 + lane * 8]);
    #pragma unroll
    for (int j = 0; j < 4; ++j)
      bfh[j] = *reinterpret_cast<const bf16x8*>(&Bh[(wc*4 + j) * 512 + lane * 8]);
    #pragma unroll
    for (int i = 0; i < 4; ++i)
      #pragma unroll
      for (int j = 0; j < 4; ++j)
        acc[i][j] = __builtin_amdgcn_mfma_f32_16x16x32_bf16(afh[i], bfh[j], acc[i][j], 0, 0, 0);

    bf16x8 bfl[4];
    #pragma unroll
    for (int j = 0; j < 4; ++j)
      bfl[j] = *reinterpret_cast<const bf16x8*>(&Bl[(wc*4 + j) * 512 + lane * 8]);
    #pragma unroll
    for (int i = 0; i < 4; ++i)
      #pragma unroll
      for (int j = 0; j < 4; ++j)
        acc[i][j] = __builtin_amdgcn_mfma_f32_16x16x32_bf16(afh[i], bfl[j], acc[i][j], 0, 0, 0);

    bf16x8 afl[4];
    #pragma unroll
    for (int i = 0; i < 4; ++i)
      afl[i] = *reinterpret_cast<const bf16x8*>(&Al[(wr*4 + i) * 512 + lane * 8]);
    #pragma unroll
    for (int i = 0; i < 4; ++i)
      #pragma unroll
      for (int j = 0; j < 4; ++j)
        acc[i][j] = __builtin_amdgcn_mfma_f32_16x16x32_bf16(afl[i], bfh[j], acc[i][j], 0, 0, 0);
  }

  const int mb = m0 + wr * 64 + (lane >> 4) * 4;
  const int nb = n0 + wc * 64 + (lane & 15);
  #pragma unroll
  for (int j = 0; j < 4; ++j){
    int n = nb + j * 16;
    if (n >= N_) continue;
    float si = sinv[n];
    #pragma unroll
    for (int i = 0; i < 4; ++i){
      #pragma unroll
      for (int r = 0; r < 4; ++r){
        int m = mb + i * 16 + r;
        Out[(long)m * N_ + n] = acc[i][j][r] * zinv[m] * si;
      }
    }
  }
}

// Fused norm+dot GEMM (R7 mfma_be core, new epilogue).
// A = SZ [MR_][D1_] bf16 (S rows then z rows); Bw [NEX_][D1_] bf16.
// n0 <  NE_:  atomicAdd per-row sum of (gamma*v+bias)^2 into norm2[m][e]
// n0 >= NE_:  dots[m][n-NE_] = raw v  (G columns already carry alpha/gamma/cn)
__global__ __launch_bounds__(256)
void mfma_norm_dots(const unsigned short* __restrict__ A,
                    const unsigned short* __restrict__ Bw,
                    const float* __restrict__ gamma,   // [NE_]
                    const float* __restrict__ bias,    // [NE_]
                    float* __restrict__ norm2,         // [MR_][E_]
                    float* __restrict__ dots)          // [MR_][NDOT_]
{
  __shared__ unsigned short Alds[128 * 32];
  __shared__ unsigned short Blds[128 * 32];
  const int n0 = blockIdx.x * 128;
  const int m0 = blockIdx.y * 128;
  const int t  = threadIdx.x;
  const int lane = t & 63;
  const int w  = t >> 6;
  const int wr = w >> 1, wc = w & 1;
  const int r15 = lane & 15, kb = lane >> 4;

  const unsigned short* ga0 = A  + (long)(m0 + 32*w      + r15) * D1_ + kb * 8;
  const unsigned short* ga1 = A  + (long)(m0 + 32*w + 16 + r15) * D1_ + kb * 8;
  const unsigned short* gb0 = Bw + (long)(n0 + 32*w      + r15) * D1_ + kb * 8;
  const unsigned short* gb1 = Bw + (long)(n0 + 32*w + 16 + r15) * D1_ + kb * 8;
  unsigned short* la0 = &Alds[(2*w)   * 512];
  unsigned short* la1 = &Alds[(2*w+1) * 512];
  unsigned short* lb0 = &Blds[(2*w)   * 512];
  unsigned short* lb1 = &Blds[(2*w+1) * 512];

  f32x4 acc[4][4];
  #pragma unroll
  for (int i = 0; i < 4; ++i)
    #pragma unroll
    for (int j = 0; j < 4; ++j)
      acc[i][j] = (f32x4){0.f, 0.f, 0.f, 0.f};

  for (int k0 = 0; k0 < D1_; k0 += 32){
    __syncthreads();
    gload_lds16(ga0 + k0, la0);
    gload_lds16(ga1 + k0, la1);
    gload_lds16(gb0 + k0, lb0);
    gload_lds16(gb1 + k0, lb1);
    __syncthreads();

    bf16x8 af[4], bfv[4];
    #pragma unroll
    for (int i = 0; i < 4; ++i)
      af[i] = *reinterpret_cast<const bf16x8*>(&Alds[(wr*4 + i) * 512 + lane * 8]);
    #pragma unroll
    for (int j = 0; j < 4; ++j)
      bfv[j] = *reinterpret_cast<const bf16x8*>(&Blds[(wc*4 + j) * 512 + lane * 8]);
    #pragma unroll
    for (int i = 0; i < 4; ++i)
      #pragma unroll
      for (int j = 0; j < 4; ++j)
        acc[i][j] = __builtin_amdgcn_mfma_f32_16x16x32_bf16(af[i], bfv[j], acc[i][j], 0, 0, 0);
  }

  if (n0 < NE_){
    const int e = n0 >> 10;
    float g4[4], b4[4];
    #pragma unroll
    for (int j = 0; j < 4; ++j){
      int n = n0 + wc * 64 + r15 + j * 16;
      g4[j] = gamma[n]; b4[j] = bias[n];
    }
    float rs[16];
    #pragma unroll
    for (int i = 0; i < 4; ++i)
      #pragma unroll
      for (int r = 0; r < 4; ++r){
        float s = 0.f;
        #pragma unroll
        for (int j = 0; j < 4; ++j){
          float v = acc[i][j][r] * g4[j] + b4[j];
          s += v * v;
        }
        rs[i*4 + r] = s;
      }
    #pragma unroll
    for (int msk = 1; msk < 16; msk <<= 1)
      #pragma unroll
      for (int q = 0; q < 16; ++q) rs[q] += __shfl_xor(rs[q], msk);
    __syncthreads();                      // done with Alds as LDS tiles
    float* red = (float*)Alds;            // [2][128]
    if (r15 == 0){
      int rb = wr * 64 + kb * 4;
      #pragma unroll
      for (int i = 0; i < 4; ++i)
        #pragma unroll
        for (int r = 0; r < 4; ++r)
          red[wc * 128 + rb + i*16 + r] = rs[i*4 + r];
    }
    __syncthreads();
    if (t < 128){
      float v = red[t] + red[128 + t];
      atomicAdd(&norm2[(long)(m0 + t) * E_ + e], v);
    }
  } else {
    const int dc0 = n0 - NE_ + wc * 64 + r15;
    const int mb = m0 + wr * 64 + kb * 4;
    #pragma unroll
    for (int j = 0; j < 4; ++j){
      int dc = dc0 + j * 16;
      #pragma unroll
      for (int i = 0; i < 4; ++i)
        #pragma unroll
        for (int r = 0; r < 4; ++r)
          dots[(long)(mb + i*16 + r) * NDOT_ + dc] = acc[i][j][r];
    }
  }
}

// register-resident top-20 (value desc, tie -> lower index) per row of scores[B_][N_]
__global__ __launch_bounds__(256)
void topk20(const float* __restrict__ scores, int* __restrict__ idx){
  const int b = blockIdx.x, t = threadIdx.x;
  const int l = t & 63, wid = t >> 6;
  const float* row = scores + (long)b * N_;
  float v[14];
  #pragma unroll
  for (int j = 0; j < 14; ++j){
    int i = t + j * 256;
    v[j] = (i < N_) ? row[i] : -3.0e38f;
  }
  __shared__ float wv[4];
  __shared__ int   wi[4];
  for (int it = 0; it < TOPK_; ++it){
    float bv = -3.0e38f; int bj = 0;
    #pragma unroll
    for (int j = 0; j < 14; ++j)
      if (v[j] > bv){ bv = v[j]; bj = j; }
    int bi = t + bj * 256;
    #pragma unroll
    for (int m = 1; m < 64; m <<= 1){
      float ov = __shfl_xor(bv, m);
      int   oi = __shfl_xor(bi, m);
      if (ov > bv || (ov == bv && oi < bi)){ bv = ov; bi = oi; }
    }
    if (l == 0){ wv[wid] = bv; wi[wid] = bi; }
    __syncthreads();
    float gv = wv[0]; int gi = wi[0];
    #pragma unroll
    for (int k = 1; k < 4; ++k){
      float ov = wv[k]; int oi = wi[k];
      if (ov > gv || (ov == gv && oi < gi)){ gv = ov; gi = oi; }
    }
    if (t == 0) idx[b * TOPK_ + it] = gi;
    const int ot = gi & 255, oj = gi >> 8;
    #pragma unroll
    for (int j = 0; j < 14; ++j)
      if (t == ot && j == oj) v[j] = -3.0e38f;
    __syncthreads();
  }
}

// soft[e][n][c] = softmax_c( TAU*(dots[n][ec]+bconst[ec]) / max(sqrt(norm2[n][e]),eps) )
__global__ __launch_bounds__(256)
void soft_build(const float* __restrict__ dots, const float* __restrict__ norm2,
                const float* __restrict__ bconst, float* __restrict__ soft){
  int id = blockIdx.x * 256 + threadIdx.x;
  if (id >= N_ * E_) return;
  int e = id % E_, n = id / E_;
  float rinv = 1.f / fmaxf(sqrtf(norm2[(long)n * E_ + e]), 1e-12f);
  float tv[C_];
  #pragma unroll
  for (int c = 0; c < C_; ++c)
    tv[c] = TAU_ * (dots[(long)n * NDOT_ + e*C_ + c] + bconst[e*C_ + c]) * rinv;
  float m = tv[0];
  #pragma unroll
  for (int c = 1; c < C_; ++c) m = fmaxf(m, tv[c]);
  float p[C_]; float sum = 0.f;
  #pragma unroll
  for (int c = 0; c < C_; ++c){ p[c] = expf(tv[c] - m); sum += p[c]; }
  float is = 1.f / sum;
  #pragma unroll
  for (int c = 0; c < C_; ++c)
    soft[((long)e * N_ + n) * C_ + c] = p[c] * is;
}

// logits[e][b][c] = TAU*(dots[ZOFF_+b][ec]+bconst[ec]) / max(sqrt(norm2[ZOFF_+b][e]),eps)
__global__ __launch_bounds__(256)
void logits_fin(const float* __restrict__ dots, const float* __restrict__ norm2,
                const float* __restrict__ bconst, float* __restrict__ out){
  int id = blockIdx.x * 256 + threadIdx.x;
  if (id >= B_ * E_) return;
  int e = id % E_, b = id / E_;
  int m = ZOFF_ + b;
  float rinv = 1.f / fmaxf(sqrtf(norm2[(long)m * E_ + e]), 1e-12f);
  float* op = out + (size_t)B_ * C_ + ((long)e * B_ + b) * C_;
  #pragma unroll
  for (int c = 0; c < C_; ++c)
    op[c] = TAU_ * (dots[(long)m * NDOT_ + e*C_ + c] + bconst[e*C_ + c]) * rinv;
}

__global__ __launch_bounds__(256)
void outputs_k(const float* __restrict__ soft, const int* __restrict__ idx, float* __restrict__ out){
  const int lane = threadIdx.x & 63;
  const int b = blockIdx.x * 4 + (threadIdx.x >> 6);
  const int* id = idx + b * TOPK_;
  float o = 0.f;
  for (int e = 0; e < E_; ++e){
    float S = 0.f;
    const float* se = soft + (long)e * N_ * C_;
    #pragma unroll
    for (int k = 0; k < TOPK_; ++k){
      int n = id[k];
      if (lane < C_) S += se[(long)n * C_ + lane];
    }
    float tot = wsum64(S);
    o += S / (tot + 1e-12f);
  }
  if (lane < C_) out[(long)b * C_ + lane] = o * (1.f / E_);
}

extern "C" void kernel_launch(void* const* d_in, const int* in_sizes, int n_in,
                              void* d_out, int out_size, void* d_ws, size_t ws_size,
                              hipStream_t stream){
  const float* z        = (const float*)d_in[0];
  const float* supports = (const float*)d_in[1];
  const float* labels   = (const float*)d_in[2];
  const float* weight   = (const float*)d_in[3];
  const float* alpha    = (const float*)d_in[4];
  const float* gamma    = (const float*)d_in[5];
  const float* bias     = (const float*)d_in[6];
  float* out = (float*)d_out;

  char* w = (char*)d_ws;
  size_t off = 0;
  auto alloc = [&](size_t bytes)->char*{
    char* p = w + off;
    off = (off + bytes + 255) & ~(size_t)255;
    return p;
  };

  // ---- all-permanent layout (~185 MB, no overlay) ----
  float* zinv = (float*)alloc((size_t)B_ * 4);
  float* sinv = (float*)alloc((size_t)N_ * 4);
  float* cnt  = (float*)alloc((size_t)C_ * 4);
  int*   y    = (int*)  alloc((size_t)N_ * 4);
  int*   idx  = (int*)  alloc((size_t)B_ * TOPK_ * 4);
  unsigned short* SZ  = (unsigned short*)alloc((size_t)MR_ * D1_ * 2);   // sh rows 0..3455, zh rows 3456..7551
  unsigned short* zl  = (unsigned short*)alloc((size_t)B_  * D1_ * 2);
  unsigned short* sl  = (unsigned short*)alloc((size_t)NP_ * D1_ * 2);
  unsigned short* wbf = (unsigned short*)alloc((size_t)NEX_ * D1_ * 2);  // alphaW + G cols
  float* WT     = (float*)alloc((size_t)D1_ * D2_ * 4);
  float* part   = (float*)alloc((size_t)8 * C_ * D1_ * 4);
  float* P      = (float*)alloc((size_t)C_ * D1_ * 4);
  float* A2     = (float*)alloc((size_t)EC_ * D1_ * 4);
  float* centp  = (float*)alloc((size_t)EC_ * D2_ * 4);
  float* cent   = (float*)alloc((size_t)EC_ * D2_ * 4);
  float* gcn    = (float*)alloc((size_t)EC_ * D2_ * 4);
  float* H      = (float*)alloc((size_t)EC_ * D1_ * 4);
  float* bconst = (float*)alloc((size_t)256 * 4);
  float* scores = (float*)alloc((size_t)B_ * N_ * 4);
  float* dots   = (float*)alloc((size_t)MR_ * NDOT_ * 4);
  float* norm2  = (float*)alloc((size_t)MR_ * E_ * 4);
  float* soft   = (float*)alloc((size_t)E_ * N_ * C_ * 4);
  (void)ws_size; (void)in_sizes; (void)n_in; (void)out_size;

  unsigned short* sh = SZ;
  unsigned short* zh = SZ + (size_t)ZOFF_ * D1_;

  // row norms + label prep
  rownorm_inv<<<B_, 256, 0, stream>>>(z, D1_, zinv);
  rownorm_inv<<<N_, 256, 0, stream>>>(supports, D1_, sinv);
  zero_cnt<<<1, 32, 0, stream>>>(cnt);
  labelprep<<<(N_ + 255) / 256, 256, 0, stream>>>(labels, y, cnt);

  // zero fills: sh pad, sl pad, z pad, G pad cols, norm2
  zfill<<<(14336 + 255) / 256, 256, 0, stream>>>((uint4*)(sh + (size_t)N_ * D1_), 14336);
  zfill<<<(14336 + 255) / 256, 256, 0, stream>>>((uint4*)(sl + (size_t)N_ * D1_), 14336);
  zfill<<<(32768 + 255) / 256, 256, 0, stream>>>((uint4*)(SZ + (size_t)(ZOFF_ + B_) * D1_), 32768);
  zfill<<<(22016 + 255) / 256, 256, 0, stream>>>((uint4*)(wbf + (size_t)(NE_ + EC_) * D1_), 22016);
  zfill<<<(19200 + 255) / 256, 256, 0, stream>>>((uint4*)norm2, 19200);

  // bf16 precompute
  cvt_split<<<(B_ * D1_ / 4 + 255) / 256, 256, 0, stream>>>(z, zh, zl, (long)B_ * D1_ / 4);
  cvt_split<<<(N_ * D1_ / 4 + 255) / 256, 256, 0, stream>>>(supports, sh, sl, (long)N_ * D1_ / 4);
  wfold<<<(int)((long)NE_ * D1_ / 4 / 256), 256, 0, stream>>>(weight, alpha, wbf);
  transposeW<<<dim3(D1_ / 32, D2_ / 32), 256, 0, stream>>>(weight, WT);

  // cosine scores + top-20
  mfma_scores2<<<dim3(NP_ / 128, B_ / 128, 1), 256, 0, stream>>>(
      zh, zl, sh, sl, zinv, sinv, scores);
  topk20<<<B_, 256, 0, stream>>>(scores, idx);

  // centroid path (fp32, low-rank): P -> A2 -> centpre -> cent -> normalize -> gcn -> H -> G, bconst
  pbuild<<<dim3(D1_ / 256, 8), 256, 0, stream>>>(supports, y, cnt, part);
  preduce<<<(C_ * D1_ + 255) / 256, 256, 0, stream>>>(part, P);
  a2build<<<(EC_ * D1_ + 255) / 256, 256, 0, stream>>>(P, alpha, A2);
  gemm64<<<dim3(D2_ / 64, (EC_ + 63) / 64), 256, 0, stream>>>(
      A2, D1_, weight, D1_, centp, D2_, EC_, D2_, D1_);
  centscale<<<(EC_ * D2_ + 255) / 256, 256, 0, stream>>>(centp, gamma, bias, cnt, cent);
  rownorm_inplace<<<EC_, 256, 0, stream>>>(cent, D2_);
  gcnbuild<<<(EC_ * D2_ + 255) / 256, 256, 0, stream>>>(cent, gamma, gcn);
  gemm64<<<dim3(D1_ / 64, (EC_ + 63) / 64), 256, 0, stream>>>(
      gcn, D2_, WT, D2_, H, D1_, EC_, D1_, D2_);
  gbuild<<<(EC_ * D1_ + 255) / 256, 256, 0, stream>>>(H, alpha, wbf);
  bconst_build<<<(EC_ + 3) / 4, 256, 0, stream>>>(bias, cent, bconst);

  // fused norm+dot GEMM over all S and z rows
  mfma_norm_dots<<<dim3(NEX_ / 128, MR_ / 128, 1), 256, 0, stream>>>(
      SZ, wbf, gamma, bias, norm2, dots);

  // finalize
  soft_build<<<(N_ * E_ + 255) / 256, 256, 0, stream>>>(dots, norm2, bconst, soft);
  outputs_k<<<B_ / 4, 256, 0, stream>>>(soft, idx, out);
  logits_fin<<<(B_ * E_ + 255) / 256, 256, 0, stream>>>(dots, norm2, bconst, out);
}

// Round 10
// 1202.144 us; speedup vs baseline: 1.2774x; 1.1292x over previous
//
#include <hip/hip_runtime.h>
#include <math.h>

#define B_    4096
#define N_    3400
#define NP_   3456          // N_ padded to 128 (scores tile grid)
#define D1_   2048
#define D2_   1024
#define E_    10
#define NE_   (E_ * D2_)    // 10240 fused ensemble columns
#define NDOT_ 256           // extra dot columns (170 used)
#define NEX_  (NE_ + NDOT_) // 10496
#define ZOFF_ 3456          // z rows start in SZ
#define MR_   7680          // SZ total rows (3456 S + 4096 z + 128 pad)
#define EC_   170           // E_*C_
#define C_    17
#define TOPK_ 20
#define TAU_  10.0f

typedef __bf16 bf16x8 __attribute__((ext_vector_type(8)));
typedef __bf16 bf16x4 __attribute__((ext_vector_type(4)));
typedef float  f32x4  __attribute__((ext_vector_type(4)));

#define MFMA_(a,b,c) __builtin_amdgcn_mfma_f32_16x16x32_bf16(a,b,c,0,0,0)

__device__ inline float wsum64(float v){
  #pragma unroll
  for (int m = 1; m < 64; m <<= 1) v += __shfl_xor(v, m);
  return v;
}

__device__ __forceinline__ void gload_lds16(const unsigned short* g, unsigned short* l){
  __builtin_amdgcn_global_load_lds(
      (const __attribute__((address_space(1))) void*)g,
      (__attribute__((address_space(3))) void*)l, 16, 0, 0);
}

// --- row 1/max(||x||,eps) for [R][D] ---
__global__ __launch_bounds__(256)
void rownorm_inv(const float* __restrict__ X, int D, float* __restrict__ rinv){
  int r = blockIdx.x, t = threadIdx.x;
  const float4* x4 = reinterpret_cast<const float4*>(X + (long)r * D);
  float ss = 0.f;
  for (int i = t; i < (D >> 2); i += 256){
    float4 v = x4[i];
    ss += v.x*v.x + v.y*v.y + v.z*v.z + v.w*v.w;
  }
  __shared__ float red[256];
  red[t] = ss; __syncthreads();
  for (int s = 128; s; s >>= 1){ if (t < s) red[t] += red[t + s]; __syncthreads(); }
  if (t == 0) rinv[r] = 1.f / fmaxf(sqrtf(red[0]), 1e-12f);
}

__global__ void zero_cnt(float* cnt){ if (threadIdx.x < C_) cnt[threadIdx.x] = 0.f; }

__global__ __launch_bounds__(256)
void zfill(uint4* __restrict__ p, long n){
  long i = (long)blockIdx.x * 256 + threadIdx.x;
  if (i < n) p[i] = make_uint4(0,0,0,0);
}

__global__ __launch_bounds__(256)
void labelprep(const float* __restrict__ labels, int* __restrict__ y, float* __restrict__ cnt){
  int n = blockIdx.x * 256 + threadIdx.x;
  if (n >= N_) return;
  int c = 0;
  #pragma unroll
  for (int cc = 0; cc < C_; ++cc) if (labels[n * C_ + cc] > 0.5f) c = cc;
  y[n] = c;
  atomicAdd(&cnt[c], 1.0f);
}

// fp32 -> (hi bf16, lo bf16 of exact residual)
__global__ __launch_bounds__(256)
void cvt_split(const float* __restrict__ src, unsigned short* __restrict__ hi,
               unsigned short* __restrict__ lo, long n4){
  long i = (long)blockIdx.x * 256 + threadIdx.x;
  if (i >= n4) return;
  float4 v = reinterpret_cast<const float4*>(src)[i];
  float f[4] = {v.x, v.y, v.z, v.w};
  bf16x4 h4, l4;
  #pragma unroll
  for (int j = 0; j < 4; ++j){
    __bf16 h = (__bf16)f[j];
    h4[j] = h;
    l4[j] = (__bf16)(f[j] - (float)h);
  }
  reinterpret_cast<bf16x4*>(hi)[i] = h4;
  reinterpret_cast<bf16x4*>(lo)[i] = l4;
}

// Wbf[e][n][k] = bf16(alpha[e][k] * W[n][k]),  laid out [NE_][D1_]
__global__ __launch_bounds__(256)
void wfold(const float* __restrict__ W, const float* __restrict__ alpha,
           unsigned short* __restrict__ wbf){
  long i = (long)blockIdx.x * 256 + threadIdx.x;       // float4 units
  const long perE = (long)D2_ * D1_ / 4;
  int e = (int)(i / perE);
  long r = i - (long)e * perE;
  int k4 = (int)(r & (D1_/4 - 1));
  float4 wv = reinterpret_cast<const float4*>(W)[r];
  float4 av = reinterpret_cast<const float4*>(alpha + (long)e * D1_)[k4];
  bf16x4 o;
  o[0] = (__bf16)(wv.x * av.x);
  o[1] = (__bf16)(wv.y * av.y);
  o[2] = (__bf16)(wv.z * av.z);
  o[3] = (__bf16)(wv.w * av.w);
  reinterpret_cast<bf16x4*>(wbf)[i] = o;
}

// WT[k][d] = W[d][k]
__global__ __launch_bounds__(256)
void transposeW(const float* __restrict__ W, float* __restrict__ WT){
  __shared__ float tile[32][33];
  const int bx = blockIdx.x, by = blockIdx.y;
  const int tx = threadIdx.x & 31, ty = threadIdx.x >> 5;
  #pragma unroll
  for (int i = 0; i < 4; ++i)
    tile[ty + i*8][tx] = W[(long)(by*32 + ty + i*8) * D1_ + bx*32 + tx];
  __syncthreads();
  #pragma unroll
  for (int i = 0; i < 4; ++i)
    WT[(long)(bx*32 + ty + i*8) * D2_ + by*32 + tx] = tile[tx][ty + i*8];
}

// partial P: part[s][c][k] = sum_{n in slice s, y[n]=c} S[n,k]/(cnt_c+eps)
__global__ __launch_bounds__(256)
void pbuild(const float* __restrict__ S, const int* __restrict__ y,
            const float* __restrict__ cnt, float* __restrict__ part){
  __shared__ float acc[C_ * 256];
  __shared__ float winv[C_];
  const int t = threadIdx.x, kb = blockIdx.x * 256, s = blockIdx.y;
  #pragma unroll
  for (int c = 0; c < C_; ++c) acc[c * 256 + t] = 0.f;
  if (t < C_) winv[t] = 1.f / (cnt[t] + 1e-12f);
  __syncthreads();
  const int n0 = s * 425, n1 = n0 + 425;
  for (int n = n0; n < n1; ++n){
    int c = y[n];
    acc[c * 256 + t] += winv[c] * S[(long)n * D1_ + kb + t];
  }
  #pragma unroll
  for (int c = 0; c < C_; ++c)
    part[((long)s * C_ + c) * D1_ + kb + t] = acc[c * 256 + t];
}

__global__ __launch_bounds__(256)
void preduce(const float* __restrict__ part, float* __restrict__ P){
  int i = blockIdx.x * 256 + threadIdx.x;
  if (i >= C_ * D1_) return;
  float s = 0.f;
  #pragma unroll
  for (int k = 0; k < 8; ++k) s += part[(long)k * C_ * D1_ + i];
  P[i] = s;
}

// A2[ec][k] = P[c][k]*alpha[e][k]
__global__ __launch_bounds__(256)
void a2build(const float* __restrict__ P, const float* __restrict__ alpha,
             float* __restrict__ A2){
  int i = blockIdx.x * 256 + threadIdx.x;
  if (i >= EC_ * D1_) return;
  int ec = i >> 11, k = i & (D1_ - 1);
  int e = ec / C_, c = ec - e * C_;
  A2[i] = P[c * D1_ + k] * alpha[(long)e * D1_ + k];
}

// cent[ec][d] = gamma[e][d]*pre[ec][d] + bias[e][d]*s_c
__global__ __launch_bounds__(256)
void centscale(const float* __restrict__ pre, const float* __restrict__ gamma,
               const float* __restrict__ bias, const float* __restrict__ cnt,
               float* __restrict__ cent){
  int i = blockIdx.x * 256 + threadIdx.x;
  if (i >= EC_ * D2_) return;
  int ec = i >> 10, d = i & (D2_ - 1);
  int e = ec / C_, c = ec - e * C_;
  float sc = cnt[c] / (cnt[c] + 1e-12f);
  cent[i] = gamma[(long)e * D2_ + d] * pre[i] + bias[(long)e * D2_ + d] * sc;
}

__global__ __launch_bounds__(256)
void rownorm_inplace(float* __restrict__ X, int D){
  int r = blockIdx.x, t = threadIdx.x;
  float4* x4 = reinterpret_cast<float4*>(X + (long)r * D);
  float ss = 0.f;
  for (int i = t; i < (D >> 2); i += 256){
    float4 v = x4[i];
    ss += v.x*v.x + v.y*v.y + v.z*v.z + v.w*v.w;
  }
  __shared__ float red[256];
  red[t] = ss; __syncthreads();
  for (int s2 = 128; s2; s2 >>= 1){ if (t < s2) red[t] += red[t + s2]; __syncthreads(); }
  float rinv = 1.f / fmaxf(sqrtf(red[0]), 1e-12f);
  for (int i = t; i < (D >> 2); i += 256){
    float4 v = x4[i];
    v.x *= rinv; v.y *= rinv; v.z *= rinv; v.w *= rinv;
    x4[i] = v;
  }
}

// gcn[ec][d] = gamma[e][d]*cn[ec][d]   (cn = normalized cent)
__global__ __launch_bounds__(256)
void gcnbuild(const float* __restrict__ cn, const float* __restrict__ gamma,
              float* __restrict__ gcn){
  int i = blockIdx.x * 256 + threadIdx.x;
  if (i >= EC_ * D2_) return;
  int ec = i >> 10, d = i & (D2_ - 1);
  int e = ec / C_;
  gcn[i] = gamma[(long)e * D2_ + d] * cn[i];
}

// wbf[NE_+ec][k] = bf16(alpha[e][k]*H[ec][k])
__global__ __launch_bounds__(256)
void gbuild(const float* __restrict__ H, const float* __restrict__ alpha,
            unsigned short* __restrict__ wbf){
  int i = blockIdx.x * 256 + threadIdx.x;
  if (i >= EC_ * D1_) return;
  int ec = i >> 11, k = i & (D1_ - 1);
  int e = ec / C_;
  float v = alpha[(long)e * D1_ + k] * H[i];
  __bf16 b = (__bf16)v;
  wbf[(long)(NE_ + ec) * D1_ + k] = *(unsigned short*)&b;
}

// bconst[ec] = sum_d bias[e][d]*cn[ec][d]
__global__ __launch_bounds__(256)
void bconst_build(const float* __restrict__ bias, const float* __restrict__ cn,
                  float* __restrict__ bconst){
  const int wv = threadIdx.x >> 6, l = threadIdx.x & 63;
  const int ec = blockIdx.x * 4 + wv;
  if (ec >= EC_) return;
  const int e = ec / C_;
  float s = 0.f;
  #pragma unroll
  for (int j = 0; j < 16; ++j){
    int d = l + j * 64;
    s += bias[(long)e * D2_ + d] * cn[(long)ec * D2_ + d];
  }
  s = wsum64(s);
  if (l == 0) bconst[ec] = s;
}

// fp32 vector GEMM (small problems): Out[m][n] = sum_k A[m,k]*B[n,k]
__global__ __launch_bounds__(256)
void gemm64(const float* __restrict__ A, int lda,
            const float* __restrict__ Bm, int ldb,
            float* __restrict__ Out, int ldo,
            int M, int N, int K)
{
  __shared__ float As[16][68];
  __shared__ float Bs[16][68];
  const int m0 = blockIdx.y * 64, n0 = blockIdx.x * 64;
  const int t  = threadIdx.x;
  const int lr = t >> 2;
  const int lk = (t & 3) << 2;
  const int ty4 = (t >> 4) << 2;
  const int tx4 = (t & 15) << 2;
  const bool aok = (m0 + lr) < M;
  const bool bok = (n0 + lr) < N;
  const float* ap = A  + (long)(m0 + lr) * lda + lk;
  const float* bp = Bm + (long)(n0 + lr) * ldb + lk;
  float acc[4][4] = {{0.f}};
  for (int k0 = 0; k0 < K; k0 += 16){
    float4 av = make_float4(0,0,0,0), bv = make_float4(0,0,0,0);
    if (aok) av = *reinterpret_cast<const float4*>(ap + k0);
    if (bok) bv = *reinterpret_cast<const float4*>(bp + k0);
    As[lk+0][lr] = av.x; As[lk+1][lr] = av.y; As[lk+2][lr] = av.z; As[lk+3][lr] = av.w;
    Bs[lk+0][lr] = bv.x; Bs[lk+1][lr] = bv.y; Bs[lk+2][lr] = bv.z; Bs[lk+3][lr] = bv.w;
    __syncthreads();
    #pragma unroll
    for (int kk = 0; kk < 16; ++kk){
      float4 a = *reinterpret_cast<const float4*>(&As[kk][ty4]);
      float4 b = *reinterpret_cast<const float4*>(&Bs[kk][tx4]);
      float aa[4] = {a.x, a.y, a.z, a.w};
      float bb[4] = {b.x, b.y, b.z, b.w};
      #pragma unroll
      for (int i = 0; i < 4; ++i)
        #pragma unroll
        for (int j = 0; j < 4; ++j)
          acc[i][j] += aa[i] * bb[j];
    }
    __syncthreads();
  }
  #pragma unroll
  for (int i = 0; i < 4; ++i){
    int m = m0 + ty4 + i;
    if (m >= M) continue;
    #pragma unroll
    for (int j = 0; j < 4; ++j){
      int n = n0 + tx4 + j;
      if (n >= N) continue;
      Out[(long)m * ldo + n] = acc[i][j];
    }
  }
}

// scores[m][n] = zinv[m]*sinv[n]*(Z·S) via split-bf16 3-term MFMA (known-good)
__global__ __launch_bounds__(256)
void mfma_scores2(const unsigned short* __restrict__ zh, const unsigned short* __restrict__ zl,
                  const unsigned short* __restrict__ sh, const unsigned short* __restrict__ sl,
                  const float* __restrict__ zinv, const float* __restrict__ sinv,
                  float* __restrict__ Out)
{
  __shared__ unsigned short Ah[128 * 32];
  __shared__ unsigned short Al[128 * 32];
  __shared__ unsigned short Bh[128 * 32];
  __shared__ unsigned short Bl[128 * 32];
  const int n0 = blockIdx.x * 128;
  const int m0 = blockIdx.y * 128;
  const int t  = threadIdx.x;
  const int lane = t & 63;
  const int w  = t >> 6;
  const int wr = w >> 1, wc = w & 1;
  const int r15 = lane & 15, kb = lane >> 4;

  const long arow0 = (long)(m0 + 32*w      + r15) * D1_ + kb * 8;
  const long arow1 = (long)(m0 + 32*w + 16 + r15) * D1_ + kb * 8;
  const long brow0 = (long)(n0 + 32*w      + r15) * D1_ + kb * 8;
  const long brow1 = (long)(n0 + 32*w + 16 + r15) * D1_ + kb * 8;
  const unsigned s0 = (2*w) * 512, s1 = (2*w+1) * 512;

  f32x4 acc[4][4];
  #pragma unroll
  for (int i = 0; i < 4; ++i)
    #pragma unroll
    for (int j = 0; j < 4; ++j)
      acc[i][j] = (f32x4){0.f, 0.f, 0.f, 0.f};

  for (int k0 = 0; k0 < D1_; k0 += 32){
    __syncthreads();
    gload_lds16(zh + arow0 + k0, &Ah[s0]);
    gload_lds16(zh + arow1 + k0, &Ah[s1]);
    gload_lds16(zl + arow0 + k0, &Al[s0]);
    gload_lds16(zl + arow1 + k0, &Al[s1]);
    gload_lds16(sh + brow0 + k0, &Bh[s0]);
    gload_lds16(sh + brow1 + k0, &Bh[s1]);
    gload_lds16(sl + brow0 + k0, &Bl[s0]);
    gload_lds16(sl + brow1 + k0, &Bl[s1]);
    __syncthreads();

    bf16x8 afh[4], bfh[4];
    #pragma unroll
    for (int i = 0; i < 4; ++i)
      afh[i] = *reinterpret_cast<const bf16x8*>(&Ah[(wr*4 + i) * 512 + lane * 8]);
    #pragma unroll
    for (int j = 0; j < 4; ++j)
      bfh[j] = *reinterpret_cast<const bf16x8*>(&Bh[(wc*4 + j) * 512 + lane * 8]);
    #pragma unroll
    for (int i = 0; i < 4; ++i)
      #pragma unroll
      for (int j = 0; j < 4; ++j)
        acc[i][j] = __builtin_amdgcn_mfma_f32_16x16x32_bf16(afh[i], bfh[j], acc[i][j], 0, 0, 0);

    bf16x8 bfl[4];
    #pragma unroll
    for (int j = 0; j < 4; ++j)
      bfl[j] = *reinterpret_cast<const bf16x8*>(&Bl[(wc*4 + j) * 512 + lane * 8]);
    #pragma unroll
    for (int i = 0; i < 4; ++i)
      #pragma unroll
      for (int j = 0; j < 4; ++j)
        acc[i][j] = __builtin_amdgcn_mfma_f32_16x16x32_bf16(afh[i], bfl[j], acc[i][j], 0, 0, 0);

    bf16x8 afl[4];
    #pragma unroll
    for (int i = 0; i < 4; ++i)
      afl[i] = *reinterpret_cast<const bf16x8*>(&Al[(wr*4 + i) * 512 + lane * 8]);
    #pragma unroll
    for (int i = 0; i < 4; ++i)
      #pragma unroll
      for (int j = 0; j < 4; ++j)
        acc[i][j] = __builtin_amdgcn_mfma_f32_16x16x32_bf16(afl[i], bfh[j], acc[i][j], 0, 0, 0);
  }

  const int mb = m0 + wr * 64 + (lane >> 4) * 4;
  const int nb = n0 + wc * 64 + (lane & 15);
  #pragma unroll
  for (int j = 0; j < 4; ++j){
    int n = nb + j * 16;
    if (n >= N_) continue;
    float si = sinv[n];
    #pragma unroll
    for (int i = 0; i < 4; ++i){
      #pragma unroll
      for (int r = 0; r < 4; ++r){
        int m = mb + i * 16 + r;
        Out[(long)m * N_ + n] = acc[i][j][r] * zinv[m] * si;
      }
    }
  }
}

// ==== Fused norm+dot GEMM, minimum-2-phase 256x256 BK=64 (T3 recipe) ====
// 8 waves (2M x 4N), per-wave C = 128x64. One s_barrier per K-tile; stage
// K-tile kt+1 BEFORE ds_read of kt; lgkmcnt(0)+sched_barrier before MFMA;
// vmcnt(0)+barrier at tile end. Fragment-linear LDS (0 bank conflicts).
__global__ __launch_bounds__(512)
void nd2(const unsigned short* __restrict__ A,
         const unsigned short* __restrict__ Bw,
         const float* __restrict__ gamma,   // [NE_]
         const float* __restrict__ bias,    // [NE_]
         float* __restrict__ norm2,         // [MR_][E_]
         float* __restrict__ dots)          // [MR_][NDOT_]
{
  __shared__ unsigned short LA[2][16384];
  __shared__ unsigned short LB[2][16384];
  const int n0 = blockIdx.x * 256;
  const int m0 = blockIdx.y * 256;
  const int t = threadIdx.x, lane = t & 63, w = t >> 6;
  const int wm = w >> 2, wn = w & 3;
  const int r15 = lane & 15, kb = lane >> 4;

  const unsigned short* a0p = A  + (long)(m0 +       w*16 + r15) * D1_ + kb*8;
  const unsigned short* a1p = A  + (long)(m0 + 128 + w*16 + r15) * D1_ + kb*8;
  const unsigned short* b0p = Bw + (long)(n0 +       w*16 + r15) * D1_ + kb*8;
  const unsigned short* b1p = Bw + (long)(n0 + 128 + w*16 + r15) * D1_ + kb*8;
  const unsigned d00 = (unsigned)(w*2)*512,     d01 = (unsigned)(w*2+1)*512;
  const unsigned d10 = (unsigned)((8+w)*2)*512, d11 = (unsigned)((8+w)*2+1)*512;
  const unsigned raB = (unsigned)wm*8192 + (unsigned)lane*8;   // A sub-base (ushort)
  const unsigned rbB = (unsigned)wn*4096 + (unsigned)lane*8;   // B sub-base

#define STAGE_ND(buf, kt) do{ const int ko = (kt)*64; \
    gload_lds16(a0p+ko,    &LA[buf][d00]); gload_lds16(a0p+ko+32, &LA[buf][d01]); \
    gload_lds16(a1p+ko,    &LA[buf][d10]); gload_lds16(a1p+ko+32, &LA[buf][d11]); \
    gload_lds16(b0p+ko,    &LB[buf][d00]); gload_lds16(b0p+ko+32, &LB[buf][d01]); \
    gload_lds16(b1p+ko,    &LB[buf][d10]); gload_lds16(b1p+ko+32, &LB[buf][d11]); }while(0)

  f32x4 acc[8][4];
  #pragma unroll
  for (int i = 0; i < 8; ++i)
    #pragma unroll
    for (int j = 0; j < 4; ++j)
      acc[i][j] = (f32x4){0.f, 0.f, 0.f, 0.f};

  STAGE_ND(0, 0);
  asm volatile("s_waitcnt vmcnt(0)" ::: "memory");
  __builtin_amdgcn_sched_barrier(0);
  __builtin_amdgcn_s_barrier();

  for (int kt = 0; kt < 32; ++kt){
    const int cb = kt & 1;
    if (kt < 31) STAGE_ND(cb ^ 1, kt + 1);        // issue next-tile loads FIRST

    bf16x8 ar[4][2], br[4][2];
    // half 1: m-subtiles 0..3 + all B
    #pragma unroll
    for (int i = 0; i < 4; ++i){
      ar[i][0] = *(const bf16x8*)&LA[cb][raB + (unsigned)(i*2  )*512];
      ar[i][1] = *(const bf16x8*)&LA[cb][raB + (unsigned)(i*2+1)*512];
    }
    #pragma unroll
    for (int j = 0; j < 4; ++j){
      br[j][0] = *(const bf16x8*)&LB[cb][rbB + (unsigned)(j*2  )*512];
      br[j][1] = *(const bf16x8*)&LB[cb][rbB + (unsigned)(j*2+1)*512];
    }
    asm volatile("s_waitcnt lgkmcnt(0)" ::: "memory");
    __builtin_amdgcn_sched_barrier(0);
    __builtin_amdgcn_s_setprio(1);
    #pragma unroll
    for (int i = 0; i < 4; ++i)
      #pragma unroll
      for (int j = 0; j < 4; ++j){
        acc[i][j] = MFMA_(ar[i][0], br[j][0], acc[i][j]);
        acc[i][j] = MFMA_(ar[i][1], br[j][1], acc[i][j]);
      }
    __builtin_amdgcn_s_setprio(0);
    // half 2: m-subtiles 4..7 (reuse ar regs)
    #pragma unroll
    for (int i = 0; i < 4; ++i){
      ar[i][0] = *(const bf16x8*)&LA[cb][raB + (unsigned)((4+i)*2  )*512];
      ar[i][1] = *(const bf16x8*)&LA[cb][raB + (unsigned)((4+i)*2+1)*512];
    }
    asm volatile("s_waitcnt lgkmcnt(0)" ::: "memory");
    __builtin_amdgcn_sched_barrier(0);
    __builtin_amdgcn_s_setprio(1);
    #pragma unroll
    for (int i = 0; i < 4; ++i)
      #pragma unroll
      for (int j = 0; j < 4; ++j){
        acc[4+i][j] = MFMA_(ar[i][0], br[j][0], acc[4+i][j]);
        acc[4+i][j] = MFMA_(ar[i][1], br[j][1], acc[4+i][j]);
      }
    __builtin_amdgcn_s_setprio(0);

    asm volatile("s_waitcnt vmcnt(0)" ::: "memory");   // next tile's stages done
    __builtin_amdgcn_sched_barrier(0);
    __builtin_amdgcn_s_barrier();
  }
#undef STAGE_ND

  if (n0 < NE_){
    const int e = n0 >> 10;
    float g4[4], b4[4];
    #pragma unroll
    for (int j = 0; j < 4; ++j){
      int n = n0 + wn * 64 + j * 16 + r15;
      g4[j] = gamma[n]; b4[j] = bias[n];
    }
    float rs[32];
    #pragma unroll
    for (int i = 0; i < 8; ++i)
      #pragma unroll
      for (int r = 0; r < 4; ++r){
        float s = 0.f;
        #pragma unroll
        for (int j = 0; j < 4; ++j){
          float v = acc[i][j][r] * g4[j] + b4[j];
          s += v * v;
        }
        rs[i*4 + r] = s;
      }
    #pragma unroll
    for (int msk = 1; msk < 16; msk <<= 1)
      #pragma unroll
      for (int q = 0; q < 32; ++q) rs[q] += __shfl_xor(rs[q], msk);
    float* red = (float*)&LA[0][0];      // [8][128] floats = 4 KB
    if (r15 == 0){
      #pragma unroll
      for (int i = 0; i < 8; ++i)
        #pragma unroll
        for (int r = 0; r < 4; ++r)
          red[w * 128 + i*16 + kb*4 + r] = rs[i*4 + r];
    }
    __syncthreads();
    if (t < 256){
      int wmg = t >> 7;
      float v = 0.f;
      #pragma unroll
      for (int q = 0; q < 4; ++q)
        v += red[(wmg*4 + q) * 128 + (t & 127)];
      atomicAdd(&norm2[(long)(m0 + t) * E_ + e], v);
    }
  } else {
    const int dc0 = n0 - NE_ + wn * 64 + r15;
    const int mb = m0 + wm * 128 + kb * 4;
    #pragma unroll
    for (int j = 0; j < 4; ++j){
      int dc = dc0 + j * 16;
      #pragma unroll
      for (int i = 0; i < 8; ++i)
        #pragma unroll
        for (int r = 0; r < 4; ++r)
          dots[(long)(mb + i*16 + r) * NDOT_ + dc] = acc[i][j][r];
    }
  }
}

// register-resident top-20 (value desc, tie -> lower index) per row of scores[B_][N_]
__global__ __launch_bounds__(256)
void topk20(const float* __restrict__ scores, int* __restrict__ idx){
  const int b = blockIdx.x, t = threadIdx.x;
  const int l = t & 63, wid = t >> 6;
  const float* row = scores + (long)b * N_;
  float v[14];
  #pragma unroll
  for (int j = 0; j < 14; ++j){
    int i = t + j * 256;
    v[j] = (i < N_) ? row[i] : -3.0e38f;
  }
  __shared__ float wv[4];
  __shared__ int   wi[4];
  for (int it = 0; it < TOPK_; ++it){
    float bv = -3.0e38f; int bj = 0;
    #pragma unroll
    for (int j = 0; j < 14; ++j)
      if (v[j] > bv){ bv = v[j]; bj = j; }
    int bi = t + bj * 256;
    #pragma unroll
    for (int m = 1; m < 64; m <<= 1){
      float ov = __shfl_xor(bv, m);
      int   oi = __shfl_xor(bi, m);
      if (ov > bv || (ov == bv && oi < bi)){ bv = ov; bi = oi; }
    }
    if (l == 0){ wv[wid] = bv; wi[wid] = bi; }
    __syncthreads();
    float gv = wv[0]; int gi = wi[0];
    #pragma unroll
    for (int k = 1; k < 4; ++k){
      float ov = wv[k]; int oi = wi[k];
      if (ov > gv || (ov == gv && oi < gi)){ gv = ov; gi = oi; }
    }
    if (t == 0) idx[b * TOPK_ + it] = gi;
    const int ot = gi & 255, oj = gi >> 8;
    #pragma unroll
    for (int j = 0; j < 14; ++j)
      if (t == ot && j == oj) v[j] = -3.0e38f;
    __syncthreads();
  }
}

// soft[e][n][c] = softmax_c( TAU*(dots[n][ec]+bconst[ec]) / max(sqrt(norm2[n][e]),eps) )
__global__ __launch_bounds__(256)
void soft_build(const float* __restrict__ dots, const float* __restrict__ norm2,
                const float* __restrict__ bconst, float* __restrict__ soft){
  int id = blockIdx.x * 256 + threadIdx.x;
  if (id >= N_ * E_) return;
  int e = id % E_, n = id / E_;
  float rinv = 1.f / fmaxf(sqrtf(norm2[(long)n * E_ + e]), 1e-12f);
  float tv[C_];
  #pragma unroll
  for (int c = 0; c < C_; ++c)
    tv[c] = TAU_ * (dots[(long)n * NDOT_ + e*C_ + c] + bconst[e*C_ + c]) * rinv;
  float m = tv[0];
  #pragma unroll
  for (int c = 1; c < C_; ++c) m = fmaxf(m, tv[c]);
  float p[C_]; float sum = 0.f;
  #pragma unroll
  for (int c = 0; c < C_; ++c){ p[c] = expf(tv[c] - m); sum += p[c]; }
  float is = 1.f / sum;
  #pragma unroll
  for (int c = 0; c < C_; ++c)
    soft[((long)e * N_ + n) * C_ + c] = p[c] * is;
}

// logits[e][b][c] = TAU*(dots[ZOFF_+b][ec]+bconst[ec]) / max(sqrt(norm2[ZOFF_+b][e]),eps)
__global__ __launch_bounds__(256)
void logits_fin(const float* __restrict__ dots, const float* __restrict__ norm2,
                const float* __restrict__ bconst, float* __restrict__ out){
  int id = blockIdx.x * 256 + threadIdx.x;
  if (id >= B_ * E_) return;
  int e = id % E_, b = id / E_;
  int m = ZOFF_ + b;
  float rinv = 1.f / fmaxf(sqrtf(norm2[(long)m * E_ + e]), 1e-12f);
  float* op = out + (size_t)B_ * C_ + ((long)e * B_ + b) * C_;
  #pragma unroll
  for (int c = 0; c < C_; ++c)
    op[c] = TAU_ * (dots[(long)m * NDOT_ + e*C_ + c] + bconst[e*C_ + c]) * rinv;
}

__global__ __launch_bounds__(256)
void outputs_k(const float* __restrict__ soft, const int* __restrict__ idx, float* __restrict__ out){
  const int lane = threadIdx.x & 63;
  const int b = blockIdx.x * 4 + (threadIdx.x >> 6);
  const int* id = idx + b * TOPK_;
  float o = 0.f;
  for (int e = 0; e < E_; ++e){
    float S = 0.f;
    const float* se = soft + (long)e * N_ * C_;
    #pragma unroll
    for (int k = 0; k < TOPK_; ++k){
      int n = id[k];
      if (lane < C_) S += se[(long)n * C_ + lane];
    }
    float tot = wsum64(S);
    o += S / (tot + 1e-12f);
  }
  if (lane < C_) out[(long)b * C_ + lane] = o * (1.f / E_);
}

extern "C" void kernel_launch(void* const* d_in, const int* in_sizes, int n_in,
                              void* d_out, int out_size, void* d_ws, size_t ws_size,
                              hipStream_t stream){
  const float* z        = (const float*)d_in[0];
  const float* supports = (const float*)d_in[1];
  const float* labels   = (const float*)d_in[2];
  const float* weight   = (const float*)d_in[3];
  const float* alpha    = (const float*)d_in[4];
  const float* gamma    = (const float*)d_in[5];
  const float* bias     = (const float*)d_in[6];
  float* out = (float*)d_out;

  char* w = (char*)d_ws;
  size_t off = 0;
  auto alloc = [&](size_t bytes)->char*{
    char* p = w + off;
    off = (off + bytes + 255) & ~(size_t)255;
    return p;
  };

  // ---- all-permanent layout (~185 MB, no overlay) ----
  float* zinv = (float*)alloc((size_t)B_ * 4);
  float* sinv = (float*)alloc((size_t)N_ * 4);
  float* cnt  = (float*)alloc((size_t)C_ * 4);
  int*   y    = (int*)  alloc((size_t)N_ * 4);
  int*   idx  = (int*)  alloc((size_t)B_ * TOPK_ * 4);
  unsigned short* SZ  = (unsigned short*)alloc((size_t)MR_ * D1_ * 2);   // sh rows 0..3455, zh rows 3456..7551
  unsigned short* zl  = (unsigned short*)alloc((size_t)B_  * D1_ * 2);
  unsigned short* sl  = (unsigned short*)alloc((size_t)NP_ * D1_ * 2);
  unsigned short* wbf = (unsigned short*)alloc((size_t)NEX_ * D1_ * 2);  // alphaW + G cols
  float* WT     = (float*)alloc((size_t)D1_ * D2_ * 4);
  float* part   = (float*)alloc((size_t)8 * C_ * D1_ * 4);
  float* P      = (float*)alloc((size_t)C_ * D1_ * 4);
  float* A2     = (float*)alloc((size_t)EC_ * D1_ * 4);
  float* centp  = (float*)alloc((size_t)EC_ * D2_ * 4);
  float* cent   = (float*)alloc((size_t)EC_ * D2_ * 4);
  float* gcn    = (float*)alloc((size_t)EC_ * D2_ * 4);
  float* H      = (float*)alloc((size_t)EC_ * D1_ * 4);
  float* bconst = (float*)alloc((size_t)256 * 4);
  float* scores = (float*)alloc((size_t)B_ * N_ * 4);
  float* dots   = (float*)alloc((size_t)MR_ * NDOT_ * 4);
  float* norm2  = (float*)alloc((size_t)MR_ * E_ * 4);
  float* soft   = (float*)alloc((size_t)E_ * N_ * C_ * 4);
  (void)ws_size; (void)in_sizes; (void)n_in; (void)out_size;

  unsigned short* sh = SZ;
  unsigned short* zh = SZ + (size_t)ZOFF_ * D1_;

  // row norms + label prep
  rownorm_inv<<<B_, 256, 0, stream>>>(z, D1_, zinv);
  rownorm_inv<<<N_, 256, 0, stream>>>(supports, D1_, sinv);
  zero_cnt<<<1, 32, 0, stream>>>(cnt);
  labelprep<<<(N_ + 255) / 256, 256, 0, stream>>>(labels, y, cnt);

  // zero fills: sh pad, sl pad, z pad, G pad cols, norm2
  zfill<<<(14336 + 255) / 256, 256, 0, stream>>>((uint4*)(sh + (size_t)N_ * D1_), 14336);
  zfill<<<(14336 + 255) / 256, 256, 0, stream>>>((uint4*)(sl + (size_t)N_ * D1_), 14336);
  zfill<<<(32768 + 255) / 256, 256, 0, stream>>>((uint4*)(SZ + (size_t)(ZOFF_ + B_) * D1_), 32768);
  zfill<<<(22016 + 255) / 256, 256, 0, stream>>>((uint4*)(wbf + (size_t)(NE_ + EC_) * D1_), 22016);
  zfill<<<(19200 + 255) / 256, 256, 0, stream>>>((uint4*)norm2, 19200);

  // bf16 precompute
  cvt_split<<<(B_ * D1_ / 4 + 255) / 256, 256, 0, stream>>>(z, zh, zl, (long)B_ * D1_ / 4);
  cvt_split<<<(N_ * D1_ / 4 + 255) / 256, 256, 0, stream>>>(supports, sh, sl, (long)N_ * D1_ / 4);
  wfold<<<(int)((long)NE_ * D1_ / 4 / 256), 256, 0, stream>>>(weight, alpha, wbf);
  transposeW<<<dim3(D1_ / 32, D2_ / 32), 256, 0, stream>>>(weight, WT);

  // cosine scores + top-20
  mfma_scores2<<<dim3(NP_ / 128, B_ / 128, 1), 256, 0, stream>>>(
      zh, zl, sh, sl, zinv, sinv, scores);
  topk20<<<B_, 256, 0, stream>>>(scores, idx);

  // centroid path (fp32, low-rank): P -> A2 -> centpre -> cent -> normalize -> gcn -> H -> G, bconst
  pbuild<<<dim3(D1_ / 256, 8), 256, 0, stream>>>(supports, y, cnt, part);
  preduce<<<(C_ * D1_ + 255) / 256, 256, 0, stream>>>(part, P);
  a2build<<<(EC_ * D1_ + 255) / 256, 256, 0, stream>>>(P, alpha, A2);
  gemm64<<<dim3(D2_ / 64, (EC_ + 63) / 64), 256, 0, stream>>>(
      A2, D1_, weight, D1_, centp, D2_, EC_, D2_, D1_);
  centscale<<<(EC_ * D2_ + 255) / 256, 256, 0, stream>>>(centp, gamma, bias, cnt, cent);
  rownorm_inplace<<<EC_, 256, 0, stream>>>(cent, D2_);
  gcnbuild<<<(EC_ * D2_ + 255) / 256, 256, 0, stream>>>(cent, gamma, gcn);
  gemm64<<<dim3(D1_ / 64, (EC_ + 63) / 64), 256, 0, stream>>>(
      gcn, D2_, WT, D2_, H, D1_, EC_, D1_, D2_);
  gbuild<<<(EC_ * D1_ + 255) / 256, 256, 0, stream>>>(H, alpha, wbf);
  bconst_build<<<(EC_ + 3) / 4, 256, 0, stream>>>(bias, cent, bconst);

  // fused norm+dot GEMM over all S and z rows (2-phase 256^2)
  nd2<<<dim3(NEX_ / 256, MR_ / 256, 1), 512, 0, stream>>>(
      SZ, wbf, gamma, bias, norm2, dots);

  // finalize
  soft_build<<<(N_ * E_ + 255) / 256, 256, 0, stream>>>(dots, norm2, bconst, soft);
  outputs_k<<<B_ / 4, 256, 0, stream>>>(soft, idx, out);
  logits_fin<<<(B_ * E_ + 255) / 256, 256, 0, stream>>>(dots, norm2, bconst, out);
}

// Round 11
// 1121.633 us; speedup vs baseline: 1.3691x; 1.0718x over previous
//
#include <hip/hip_runtime.h>
#include <math.h>

#define B_    4096
#define N_    3400
#define NP_   3456          // sl row allocation (pad to 128)
#define NP2_  3584          // scores N padded to 256 (over-read, cols discarded)
#define D1_   2048
#define D2_   1024
#define E_    10
#define NE_   (E_ * D2_)    // 10240 fused ensemble columns
#define NDOT_ 256           // extra dot columns (170 used)
#define NEX_  (NE_ + NDOT_) // 10496
#define ZOFF_ 3456          // z rows start in SZ
#define MR_   7680          // SZ total rows (3456 S + 4096 z + 128 pad)
#define EC_   170           // E_*C_
#define C_    17
#define TOPK_ 20
#define TAU_  10.0f

typedef __bf16 bf16x8 __attribute__((ext_vector_type(8)));
typedef __bf16 bf16x4 __attribute__((ext_vector_type(4)));
typedef float  f32x4  __attribute__((ext_vector_type(4)));

#define MFMA_(a,b,c) __builtin_amdgcn_mfma_f32_16x16x32_bf16(a,b,c,0,0,0)

__device__ inline float wsum64(float v){
  #pragma unroll
  for (int m = 1; m < 64; m <<= 1) v += __shfl_xor(v, m);
  return v;
}

__device__ __forceinline__ void gload_lds16(const unsigned short* g, unsigned short* l){
  __builtin_amdgcn_global_load_lds(
      (const __attribute__((address_space(1))) void*)g,
      (__attribute__((address_space(3))) void*)l, 16, 0, 0);
}

// --- row 1/max(||x||,eps) for [R][D] ---
__global__ __launch_bounds__(256)
void rownorm_inv(const float* __restrict__ X, int D, float* __restrict__ rinv){
  int r = blockIdx.x, t = threadIdx.x;
  const float4* x4 = reinterpret_cast<const float4*>(X + (long)r * D);
  float ss = 0.f;
  for (int i = t; i < (D >> 2); i += 256){
    float4 v = x4[i];
    ss += v.x*v.x + v.y*v.y + v.z*v.z + v.w*v.w;
  }
  __shared__ float red[256];
  red[t] = ss; __syncthreads();
  for (int s = 128; s; s >>= 1){ if (t < s) red[t] += red[t + s]; __syncthreads(); }
  if (t == 0) rinv[r] = 1.f / fmaxf(sqrtf(red[0]), 1e-12f);
}

__global__ void zero_cnt(float* cnt){ if (threadIdx.x < C_) cnt[threadIdx.x] = 0.f; }

__global__ __launch_bounds__(256)
void zfill(uint4* __restrict__ p, long n){
  long i = (long)blockIdx.x * 256 + threadIdx.x;
  if (i < n) p[i] = make_uint4(0,0,0,0);
}

__global__ __launch_bounds__(256)
void labelprep(const float* __restrict__ labels, int* __restrict__ y, float* __restrict__ cnt){
  int n = blockIdx.x * 256 + threadIdx.x;
  if (n >= N_) return;
  int c = 0;
  #pragma unroll
  for (int cc = 0; cc < C_; ++cc) if (labels[n * C_ + cc] > 0.5f) c = cc;
  y[n] = c;
  atomicAdd(&cnt[c], 1.0f);
}

// fp32 -> (hi bf16, lo bf16 of exact residual)
__global__ __launch_bounds__(256)
void cvt_split(const float* __restrict__ src, unsigned short* __restrict__ hi,
               unsigned short* __restrict__ lo, long n4){
  long i = (long)blockIdx.x * 256 + threadIdx.x;
  if (i >= n4) return;
  float4 v = reinterpret_cast<const float4*>(src)[i];
  float f[4] = {v.x, v.y, v.z, v.w};
  bf16x4 h4, l4;
  #pragma unroll
  for (int j = 0; j < 4; ++j){
    __bf16 h = (__bf16)f[j];
    h4[j] = h;
    l4[j] = (__bf16)(f[j] - (float)h);
  }
  reinterpret_cast<bf16x4*>(hi)[i] = h4;
  reinterpret_cast<bf16x4*>(lo)[i] = l4;
}

// Wbf[e][n][k] = bf16(alpha[e][k] * W[n][k]),  laid out [NE_][D1_]
__global__ __launch_bounds__(256)
void wfold(const float* __restrict__ W, const float* __restrict__ alpha,
           unsigned short* __restrict__ wbf){
  long i = (long)blockIdx.x * 256 + threadIdx.x;       // float4 units
  const long perE = (long)D2_ * D1_ / 4;
  int e = (int)(i / perE);
  long r = i - (long)e * perE;
  int k4 = (int)(r & (D1_/4 - 1));
  float4 wv = reinterpret_cast<const float4*>(W)[r];
  float4 av = reinterpret_cast<const float4*>(alpha + (long)e * D1_)[k4];
  bf16x4 o;
  o[0] = (__bf16)(wv.x * av.x);
  o[1] = (__bf16)(wv.y * av.y);
  o[2] = (__bf16)(wv.z * av.z);
  o[3] = (__bf16)(wv.w * av.w);
  reinterpret_cast<bf16x4*>(wbf)[i] = o;
}

// WT[k][d] = W[d][k]
__global__ __launch_bounds__(256)
void transposeW(const float* __restrict__ W, float* __restrict__ WT){
  __shared__ float tile[32][33];
  const int bx = blockIdx.x, by = blockIdx.y;
  const int tx = threadIdx.x & 31, ty = threadIdx.x >> 5;
  #pragma unroll
  for (int i = 0; i < 4; ++i)
    tile[ty + i*8][tx] = W[(long)(by*32 + ty + i*8) * D1_ + bx*32 + tx];
  __syncthreads();
  #pragma unroll
  for (int i = 0; i < 4; ++i)
    WT[(long)(bx*32 + ty + i*8) * D2_ + by*32 + tx] = tile[tx][ty + i*8];
}

// partial P: part[s][c][k] = sum_{n in slice s, y[n]=c} S[n,k]/(cnt_c+eps)
__global__ __launch_bounds__(256)
void pbuild(const float* __restrict__ S, const int* __restrict__ y,
            const float* __restrict__ cnt, float* __restrict__ part){
  __shared__ float acc[C_ * 256];
  __shared__ float winv[C_];
  const int t = threadIdx.x, kb = blockIdx.x * 256, s = blockIdx.y;
  #pragma unroll
  for (int c = 0; c < C_; ++c) acc[c * 256 + t] = 0.f;
  if (t < C_) winv[t] = 1.f / (cnt[t] + 1e-12f);
  __syncthreads();
  const int n0 = s * 425, n1 = n0 + 425;
  for (int n = n0; n < n1; ++n){
    int c = y[n];
    acc[c * 256 + t] += winv[c] * S[(long)n * D1_ + kb + t];
  }
  #pragma unroll
  for (int c = 0; c < C_; ++c)
    part[((long)s * C_ + c) * D1_ + kb + t] = acc[c * 256 + t];
}

__global__ __launch_bounds__(256)
void preduce(const float* __restrict__ part, float* __restrict__ P){
  int i = blockIdx.x * 256 + threadIdx.x;
  if (i >= C_ * D1_) return;
  float s = 0.f;
  #pragma unroll
  for (int k = 0; k < 8; ++k) s += part[(long)k * C_ * D1_ + i];
  P[i] = s;
}

// A2[ec][k] = P[c][k]*alpha[e][k]
__global__ __launch_bounds__(256)
void a2build(const float* __restrict__ P, const float* __restrict__ alpha,
             float* __restrict__ A2){
  int i = blockIdx.x * 256 + threadIdx.x;
  if (i >= EC_ * D1_) return;
  int ec = i >> 11, k = i & (D1_ - 1);
  int e = ec / C_, c = ec - e * C_;
  A2[i] = P[c * D1_ + k] * alpha[(long)e * D1_ + k];
}

// cent[ec][d] = gamma[e][d]*pre[ec][d] + bias[e][d]*s_c
__global__ __launch_bounds__(256)
void centscale(const float* __restrict__ pre, const float* __restrict__ gamma,
               const float* __restrict__ bias, const float* __restrict__ cnt,
               float* __restrict__ cent){
  int i = blockIdx.x * 256 + threadIdx.x;
  if (i >= EC_ * D2_) return;
  int ec = i >> 10, d = i & (D2_ - 1);
  int e = ec / C_, c = ec - e * C_;
  float sc = cnt[c] / (cnt[c] + 1e-12f);
  cent[i] = gamma[(long)e * D2_ + d] * pre[i] + bias[(long)e * D2_ + d] * sc;
}

__global__ __launch_bounds__(256)
void rownorm_inplace(float* __restrict__ X, int D){
  int r = blockIdx.x, t = threadIdx.x;
  float4* x4 = reinterpret_cast<float4*>(X + (long)r * D);
  float ss = 0.f;
  for (int i = t; i < (D >> 2); i += 256){
    float4 v = x4[i];
    ss += v.x*v.x + v.y*v.y + v.z*v.z + v.w*v.w;
  }
  __shared__ float red[256];
  red[t] = ss; __syncthreads();
  for (int s2 = 128; s2; s2 >>= 1){ if (t < s2) red[t] += red[t + s2]; __syncthreads(); }
  float rinv = 1.f / fmaxf(sqrtf(red[0]), 1e-12f);
  for (int i = t; i < (D >> 2); i += 256){
    float4 v = x4[i];
    v.x *= rinv; v.y *= rinv; v.z *= rinv; v.w *= rinv;
    x4[i] = v;
  }
}

// gcn[ec][d] = gamma[e][d]*cn[ec][d]   (cn = normalized cent)
__global__ __launch_bounds__(256)
void gcnbuild(const float* __restrict__ cn, const float* __restrict__ gamma,
              float* __restrict__ gcn){
  int i = blockIdx.x * 256 + threadIdx.x;
  if (i >= EC_ * D2_) return;
  int ec = i >> 10, d = i & (D2_ - 1);
  int e = ec / C_;
  gcn[i] = gamma[(long)e * D2_ + d] * cn[i];
}

// wbf[NE_+ec][k] = bf16(alpha[e][k]*H[ec][k])
__global__ __launch_bounds__(256)
void gbuild(const float* __restrict__ H, const float* __restrict__ alpha,
            unsigned short* __restrict__ wbf){
  int i = blockIdx.x * 256 + threadIdx.x;
  if (i >= EC_ * D1_) return;
  int ec = i >> 11, k = i & (D1_ - 1);
  int e = ec / C_;
  float v = alpha[(long)e * D1_ + k] * H[i];
  __bf16 b = (__bf16)v;
  wbf[(long)(NE_ + ec) * D1_ + k] = *(unsigned short*)&b;
}

// bconst[ec] = sum_d bias[e][d]*cn[ec][d]
__global__ __launch_bounds__(256)
void bconst_build(const float* __restrict__ bias, const float* __restrict__ cn,
                  float* __restrict__ bconst){
  const int wv = threadIdx.x >> 6, l = threadIdx.x & 63;
  const int ec = blockIdx.x * 4 + wv;
  if (ec >= EC_) return;
  const int e = ec / C_;
  float s = 0.f;
  #pragma unroll
  for (int j = 0; j < 16; ++j){
    int d = l + j * 64;
    s += bias[(long)e * D2_ + d] * cn[(long)ec * D2_ + d];
  }
  s = wsum64(s);
  if (l == 0) bconst[ec] = s;
}

// fp32 vector GEMM, split-K partials: part[kz][m][n] = sum_{k in chunk kz} A[m,k]*B[n,k]
__global__ __launch_bounds__(256)
void gemm64k(const float* __restrict__ A, int lda,
             const float* __restrict__ Bm, int ldb,
             float* __restrict__ part, int M, int N, int KC)
{
  __shared__ float As[16][68];
  __shared__ float Bs[16][68];
  const int kz = blockIdx.z;
  const int m0 = blockIdx.y * 64, n0 = blockIdx.x * 64;
  const int t  = threadIdx.x;
  const int lr = t >> 2;
  const int lk = (t & 3) << 2;
  const int ty4 = (t >> 4) << 2;
  const int tx4 = (t & 15) << 2;
  const bool aok = (m0 + lr) < M;
  const bool bok = (n0 + lr) < N;
  const float* ap = A  + (long)(m0 + lr) * lda + lk;
  const float* bp = Bm + (long)(n0 + lr) * ldb + lk;
  float acc[4][4] = {{0.f}};
  const int k0b = kz * KC, k0e = k0b + KC;
  for (int k0 = k0b; k0 < k0e; k0 += 16){
    float4 av = make_float4(0,0,0,0), bv = make_float4(0,0,0,0);
    if (aok) av = *reinterpret_cast<const float4*>(ap + k0);
    if (bok) bv = *reinterpret_cast<const float4*>(bp + k0);
    As[lk+0][lr] = av.x; As[lk+1][lr] = av.y; As[lk+2][lr] = av.z; As[lk+3][lr] = av.w;
    Bs[lk+0][lr] = bv.x; Bs[lk+1][lr] = bv.y; Bs[lk+2][lr] = bv.z; Bs[lk+3][lr] = bv.w;
    __syncthreads();
    #pragma unroll
    for (int kk = 0; kk < 16; ++kk){
      float4 a = *reinterpret_cast<const float4*>(&As[kk][ty4]);
      float4 b = *reinterpret_cast<const float4*>(&Bs[kk][tx4]);
      float aa[4] = {a.x, a.y, a.z, a.w};
      float bb[4] = {b.x, b.y, b.z, b.w};
      #pragma unroll
      for (int i = 0; i < 4; ++i)
        #pragma unroll
        for (int j = 0; j < 4; ++j)
          acc[i][j] += aa[i] * bb[j];
    }
    __syncthreads();
  }
  float* Out = part + (long)kz * M * N;
  #pragma unroll
  for (int i = 0; i < 4; ++i){
    int m = m0 + ty4 + i;
    if (m >= M) continue;
    #pragma unroll
    for (int j = 0; j < 4; ++j){
      int n = n0 + tx4 + j;
      if (n >= N) continue;
      Out[(long)m * N + n] = acc[i][j];
    }
  }
}

__global__ __launch_bounds__(256)
void reduceK(const float* __restrict__ part, float* __restrict__ Out, long mn){
  long i = (long)blockIdx.x * 256 + threadIdx.x;
  if (i >= mn) return;
  float s = 0.f;
  #pragma unroll
  for (int k = 0; k < 8; ++k) s += part[(long)k * mn + i];
  Out[i] = s;
}

// ==== scores GEMM, 2-phase 256x256 BK=64 (nd2 structure), flat 3-segment K ====
// scores[m][n] = zinv[m]*sinv[n]*(zh·sh + zh·sl + zl·sh), 96 K-tiles.
// B rows 3456..3583 over-read into adjacent buffers; those output cols >= N_
// are discarded by the epilogue guard (garbage confined to its own column).
__global__ __launch_bounds__(512)
void sc2(const unsigned short* __restrict__ zh, const unsigned short* __restrict__ zl,
         const unsigned short* __restrict__ sh, const unsigned short* __restrict__ sl,
         const float* __restrict__ zinv, const float* __restrict__ sinv,
         float* __restrict__ Out)
{
  __shared__ unsigned short LA[2][16384];
  __shared__ unsigned short LB[2][16384];
  const int n0 = blockIdx.x * 256;
  const int m0 = blockIdx.y * 256;
  const int t = threadIdx.x, lane = t & 63, w = t >> 6;
  const int wm = w >> 2, wn = w & 3;
  const int r15 = lane & 15, kb = lane >> 4;

  const long ao0 = (long)(m0 +       w*16 + r15) * D1_ + kb*8;
  const long ao1 = (long)(m0 + 128 + w*16 + r15) * D1_ + kb*8;
  const long bo0 = (long)(n0 +       w*16 + r15) * D1_ + kb*8;
  const long bo1 = (long)(n0 + 128 + w*16 + r15) * D1_ + kb*8;
  const unsigned d00 = (unsigned)(w*2)*512,     d01 = (unsigned)(w*2+1)*512;
  const unsigned d10 = (unsigned)((8+w)*2)*512, d11 = (unsigned)((8+w)*2+1)*512;
  const unsigned raB = (unsigned)wm*8192 + (unsigned)lane*8;
  const unsigned rbB = (unsigned)wn*4096 + (unsigned)lane*8;

#define STAGE_SC(buf, kt) do{ const int sg = (kt) >> 5; const int ko = ((kt) & 31)*64; \
    const unsigned short* ap = (sg == 2) ? zl : zh; \
    const unsigned short* bp = (sg == 1) ? sl : sh; \
    gload_lds16(ap+ao0+ko,    &LA[buf][d00]); gload_lds16(ap+ao0+ko+32, &LA[buf][d01]); \
    gload_lds16(ap+ao1+ko,    &LA[buf][d10]); gload_lds16(ap+ao1+ko+32, &LA[buf][d11]); \
    gload_lds16(bp+bo0+ko,    &LB[buf][d00]); gload_lds16(bp+bo0+ko+32, &LB[buf][d01]); \
    gload_lds16(bp+bo1+ko,    &LB[buf][d10]); gload_lds16(bp+bo1+ko+32, &LB[buf][d11]); }while(0)

  f32x4 acc[8][4];
  #pragma unroll
  for (int i = 0; i < 8; ++i)
    #pragma unroll
    for (int j = 0; j < 4; ++j)
      acc[i][j] = (f32x4){0.f, 0.f, 0.f, 0.f};

  STAGE_SC(0, 0);
  asm volatile("s_waitcnt vmcnt(0)" ::: "memory");
  __builtin_amdgcn_sched_barrier(0);
  __builtin_amdgcn_s_barrier();

  for (int kt = 0; kt < 96; ++kt){
    const int cb = kt & 1;
    if (kt < 95) STAGE_SC(cb ^ 1, kt + 1);

    bf16x8 ar[4][2], br[4][2];
    #pragma unroll
    for (int i = 0; i < 4; ++i){
      ar[i][0] = *(const bf16x8*)&LA[cb][raB + (unsigned)(i*2  )*512];
      ar[i][1] = *(const bf16x8*)&LA[cb][raB + (unsigned)(i*2+1)*512];
    }
    #pragma unroll
    for (int j = 0; j < 4; ++j){
      br[j][0] = *(const bf16x8*)&LB[cb][rbB + (unsigned)(j*2  )*512];
      br[j][1] = *(const bf16x8*)&LB[cb][rbB + (unsigned)(j*2+1)*512];
    }
    asm volatile("s_waitcnt lgkmcnt(0)" ::: "memory");
    __builtin_amdgcn_sched_barrier(0);
    __builtin_amdgcn_s_setprio(1);
    #pragma unroll
    for (int i = 0; i < 4; ++i)
      #pragma unroll
      for (int j = 0; j < 4; ++j){
        acc[i][j] = MFMA_(ar[i][0], br[j][0], acc[i][j]);
        acc[i][j] = MFMA_(ar[i][1], br[j][1], acc[i][j]);
      }
    __builtin_amdgcn_s_setprio(0);
    #pragma unroll
    for (int i = 0; i < 4; ++i){
      ar[i][0] = *(const bf16x8*)&LA[cb][raB + (unsigned)((4+i)*2  )*512];
      ar[i][1] = *(const bf16x8*)&LA[cb][raB + (unsigned)((4+i)*2+1)*512];
    }
    asm volatile("s_waitcnt lgkmcnt(0)" ::: "memory");
    __builtin_amdgcn_sched_barrier(0);
    __builtin_amdgcn_s_setprio(1);
    #pragma unroll
    for (int i = 0; i < 4; ++i)
      #pragma unroll
      for (int j = 0; j < 4; ++j){
        acc[4+i][j] = MFMA_(ar[i][0], br[j][0], acc[4+i][j]);
        acc[4+i][j] = MFMA_(ar[i][1], br[j][1], acc[4+i][j]);
      }
    __builtin_amdgcn_s_setprio(0);

    asm volatile("s_waitcnt vmcnt(0)" ::: "memory");
    __builtin_amdgcn_sched_barrier(0);
    __builtin_amdgcn_s_barrier();
  }
#undef STAGE_SC

  const int mb = m0 + wm * 128 + kb * 4;
  const int nc0 = n0 + wn * 64 + r15;
  #pragma unroll
  for (int j = 0; j < 4; ++j){
    int n = nc0 + j * 16;
    if (n >= N_) continue;
    float si = sinv[n];
    #pragma unroll
    for (int i = 0; i < 8; ++i)
      #pragma unroll
      for (int r = 0; r < 4; ++r){
        int m = mb + i*16 + r;
        Out[(long)m * N_ + n] = acc[i][j][r] * zinv[m] * si;
      }
  }
}

// ==== Fused norm+dot GEMM, minimum-2-phase 256x256 BK=64 (proven R10) ====
__global__ __launch_bounds__(512)
void nd2(const unsigned short* __restrict__ A,
         const unsigned short* __restrict__ Bw,
         const float* __restrict__ gamma,   // [NE_]
         const float* __restrict__ bias,    // [NE_]
         float* __restrict__ norm2,         // [MR_][E_]
         float* __restrict__ dots)          // [MR_][NDOT_]
{
  __shared__ unsigned short LA[2][16384];
  __shared__ unsigned short LB[2][16384];
  const int n0 = blockIdx.x * 256;
  const int m0 = blockIdx.y * 256;
  const int t = threadIdx.x, lane = t & 63, w = t >> 6;
  const int wm = w >> 2, wn = w & 3;
  const int r15 = lane & 15, kb = lane >> 4;

  const unsigned short* a0p = A  + (long)(m0 +       w*16 + r15) * D1_ + kb*8;
  const unsigned short* a1p = A  + (long)(m0 + 128 + w*16 + r15) * D1_ + kb*8;
  const unsigned short* b0p = Bw + (long)(n0 +       w*16 + r15) * D1_ + kb*8;
  const unsigned short* b1p = Bw + (long)(n0 + 128 + w*16 + r15) * D1_ + kb*8;
  const unsigned d00 = (unsigned)(w*2)*512,     d01 = (unsigned)(w*2+1)*512;
  const unsigned d10 = (unsigned)((8+w)*2)*512, d11 = (unsigned)((8+w)*2+1)*512;
  const unsigned raB = (unsigned)wm*8192 + (unsigned)lane*8;
  const unsigned rbB = (unsigned)wn*4096 + (unsigned)lane*8;

#define STAGE_ND(buf, kt) do{ const int ko = (kt)*64; \
    gload_lds16(a0p+ko,    &LA[buf][d00]); gload_lds16(a0p+ko+32, &LA[buf][d01]); \
    gload_lds16(a1p+ko,    &LA[buf][d10]); gload_lds16(a1p+ko+32, &LA[buf][d11]); \
    gload_lds16(b0p+ko,    &LB[buf][d00]); gload_lds16(b0p+ko+32, &LB[buf][d01]); \
    gload_lds16(b1p+ko,    &LB[buf][d10]); gload_lds16(b1p+ko+32, &LB[buf][d11]); }while(0)

  f32x4 acc[8][4];
  #pragma unroll
  for (int i = 0; i < 8; ++i)
    #pragma unroll
    for (int j = 0; j < 4; ++j)
      acc[i][j] = (f32x4){0.f, 0.f, 0.f, 0.f};

  STAGE_ND(0, 0);
  asm volatile("s_waitcnt vmcnt(0)" ::: "memory");
  __builtin_amdgcn_sched_barrier(0);
  __builtin_amdgcn_s_barrier();

  for (int kt = 0; kt < 32; ++kt){
    const int cb = kt & 1;
    if (kt < 31) STAGE_ND(cb ^ 1, kt + 1);

    bf16x8 ar[4][2], br[4][2];
    #pragma unroll
    for (int i = 0; i < 4; ++i){
      ar[i][0] = *(const bf16x8*)&LA[cb][raB + (unsigned)(i*2  )*512];
      ar[i][1] = *(const bf16x8*)&LA[cb][raB + (unsigned)(i*2+1)*512];
    }
    #pragma unroll
    for (int j = 0; j < 4; ++j){
      br[j][0] = *(const bf16x8*)&LB[cb][rbB + (unsigned)(j*2  )*512];
      br[j][1] = *(const bf16x8*)&LB[cb][rbB + (unsigned)(j*2+1)*512];
    }
    asm volatile("s_waitcnt lgkmcnt(0)" ::: "memory");
    __builtin_amdgcn_sched_barrier(0);
    __builtin_amdgcn_s_setprio(1);
    #pragma unroll
    for (int i = 0; i < 4; ++i)
      #pragma unroll
      for (int j = 0; j < 4; ++j){
        acc[i][j] = MFMA_(ar[i][0], br[j][0], acc[i][j]);
        acc[i][j] = MFMA_(ar[i][1], br[j][1], acc[i][j]);
      }
    __builtin_amdgcn_s_setprio(0);
    #pragma unroll
    for (int i = 0; i < 4; ++i){
      ar[i][0] = *(const bf16x8*)&LA[cb][raB + (unsigned)((4+i)*2  )*512];
      ar[i][1] = *(const bf16x8*)&LA[cb][raB + (unsigned)((4+i)*2+1)*512];
    }
    asm volatile("s_waitcnt lgkmcnt(0)" ::: "memory");
    __builtin_amdgcn_sched_barrier(0);
    __builtin_amdgcn_s_setprio(1);
    #pragma unroll
    for (int i = 0; i < 4; ++i)
      #pragma unroll
      for (int j = 0; j < 4; ++j){
        acc[4+i][j] = MFMA_(ar[i][0], br[j][0], acc[4+i][j]);
        acc[4+i][j] = MFMA_(ar[i][1], br[j][1], acc[4+i][j]);
      }
    __builtin_amdgcn_s_setprio(0);

    asm volatile("s_waitcnt vmcnt(0)" ::: "memory");
    __builtin_amdgcn_sched_barrier(0);
    __builtin_amdgcn_s_barrier();
  }
#undef STAGE_ND

  if (n0 < NE_){
    const int e = n0 >> 10;
    float g4[4], b4[4];
    #pragma unroll
    for (int j = 0; j < 4; ++j){
      int n = n0 + wn * 64 + j * 16 + r15;
      g4[j] = gamma[n]; b4[j] = bias[n];
    }
    float rs[32];
    #pragma unroll
    for (int i = 0; i < 8; ++i)
      #pragma unroll
      for (int r = 0; r < 4; ++r){
        float s = 0.f;
        #pragma unroll
        for (int j = 0; j < 4; ++j){
          float v = acc[i][j][r] * g4[j] + b4[j];
          s += v * v;
        }
        rs[i*4 + r] = s;
      }
    #pragma unroll
    for (int msk = 1; msk < 16; msk <<= 1)
      #pragma unroll
      for (int q = 0; q < 32; ++q) rs[q] += __shfl_xor(rs[q], msk);
    float* red = (float*)&LA[0][0];      // [8][128] floats = 4 KB
    if (r15 == 0){
      #pragma unroll
      for (int i = 0; i < 8; ++i)
        #pragma unroll
        for (int r = 0; r < 4; ++r)
          red[w * 128 + i*16 + kb*4 + r] = rs[i*4 + r];
    }
    __syncthreads();
    if (t < 256){
      int wmg = t >> 7;
      float v = 0.f;
      #pragma unroll
      for (int q = 0; q < 4; ++q)
        v += red[(wmg*4 + q) * 128 + (t & 127)];
      atomicAdd(&norm2[(long)(m0 + t) * E_ + e], v);
    }
  } else {
    const int dc0 = n0 - NE_ + wn * 64 + r15;
    const int mb = m0 + wm * 128 + kb * 4;
    #pragma unroll
    for (int j = 0; j < 4; ++j){
      int dc = dc0 + j * 16;
      #pragma unroll
      for (int i = 0; i < 8; ++i)
        #pragma unroll
        for (int r = 0; r < 4; ++r)
          dots[(long)(mb + i*16 + r) * NDOT_ + dc] = acc[i][j][r];
    }
  }
}

// register-resident top-20 (value desc, tie -> lower index) per row of scores[B_][N_]
__global__ __launch_bounds__(256)
void topk20(const float* __restrict__ scores, int* __restrict__ idx){
  const int b = blockIdx.x, t = threadIdx.x;
  const int l = t & 63, wid = t >> 6;
  const float* row = scores + (long)b * N_;
  float v[14];
  #pragma unroll
  for (int j = 0; j < 14; ++j){
    int i = t + j * 256;
    v[j] = (i < N_) ? row[i] : -3.0e38f;
  }
  __shared__ float wv[4];
  __shared__ int   wi[4];
  for (int it = 0; it < TOPK_; ++it){
    float bv = -3.0e38f; int bj = 0;
    #pragma unroll
    for (int j = 0; j < 14; ++j)
      if (v[j] > bv){ bv = v[j]; bj = j; }
    int bi = t + bj * 256;
    #pragma unroll
    for (int m = 1; m < 64; m <<= 1){
      float ov = __shfl_xor(bv, m);
      int   oi = __shfl_xor(bi, m);
      if (ov > bv || (ov == bv && oi < bi)){ bv = ov; bi = oi; }
    }
    if (l == 0){ wv[wid] = bv; wi[wid] = bi; }
    __syncthreads();
    float gv = wv[0]; int gi = wi[0];
    #pragma unroll
    for (int k = 1; k < 4; ++k){
      float ov = wv[k]; int oi = wi[k];
      if (ov > gv || (ov == gv && oi < gi)){ gv = ov; gi = oi; }
    }
    if (t == 0) idx[b * TOPK_ + it] = gi;
    const int ot = gi & 255, oj = gi >> 8;
    #pragma unroll
    for (int j = 0; j < 14; ++j)
      if (t == ot && j == oj) v[j] = -3.0e38f;
    __syncthreads();
  }
}

// soft[e][n][c] = softmax_c( TAU*(dots[n][ec]+bconst[ec]) / max(sqrt(norm2[n][e]),eps) )
__global__ __launch_bounds__(256)
void soft_build(const float* __restrict__ dots, const float* __restrict__ norm2,
                const float* __restrict__ bconst, float* __restrict__ soft){
  int id = blockIdx.x * 256 + threadIdx.x;
  if (id >= N_ * E_) return;
  int e = id % E_, n = id / E_;
  float rinv = 1.f / fmaxf(sqrtf(norm2[(long)n * E_ + e]), 1e-12f);
  float tv[C_];
  #pragma unroll
  for (int c = 0; c < C_; ++c)
    tv[c] = TAU_ * (dots[(long)n * NDOT_ + e*C_ + c] + bconst[e*C_ + c]) * rinv;
  float m = tv[0];
  #pragma unroll
  for (int c = 1; c < C_; ++c) m = fmaxf(m, tv[c]);
  float p[C_]; float sum = 0.f;
  #pragma unroll
  for (int c = 0; c < C_; ++c){ p[c] = expf(tv[c] - m); sum += p[c]; }
  float is = 1.f / sum;
  #pragma unroll
  for (int c = 0; c < C_; ++c)
    soft[((long)e * N_ + n) * C_ + c] = p[c] * is;
}

// logits[e][b][c] = TAU*(dots[ZOFF_+b][ec]+bconst[ec]) / max(sqrt(norm2[ZOFF_+b][e]),eps)
__global__ __launch_bounds__(256)
void logits_fin(const float* __restrict__ dots, const float* __restrict__ norm2,
                const float* __restrict__ bconst, float* __restrict__ out){
  int id = blockIdx.x * 256 + threadIdx.x;
  if (id >= B_ * E_) return;
  int e = id % E_, b = id / E_;
  int m = ZOFF_ + b;
  float rinv = 1.f / fmaxf(sqrtf(norm2[(long)m * E_ + e]), 1e-12f);
  float* op = out + (size_t)B_ * C_ + ((long)e * B_ + b) * C_;
  #pragma unroll
  for (int c = 0; c < C_; ++c)
    op[c] = TAU_ * (dots[(long)m * NDOT_ + e*C_ + c] + bconst[e*C_ + c]) * rinv;
}

__global__ __launch_bounds__(256)
void outputs_k(const float* __restrict__ soft, const int* __restrict__ idx, float* __restrict__ out){
  const int lane = threadIdx.x & 63;
  const int b = blockIdx.x * 4 + (threadIdx.x >> 6);
  const int* id = idx + b * TOPK_;
  float o = 0.f;
  for (int e = 0; e < E_; ++e){
    float S = 0.f;
    const float* se = soft + (long)e * N_ * C_;
    #pragma unroll
    for (int k = 0; k < TOPK_; ++k){
      int n = id[k];
      if (lane < C_) S += se[(long)n * C_ + lane];
    }
    float tot = wsum64(S);
    o += S / (tot + 1e-12f);
  }
  if (lane < C_) out[(long)b * C_ + lane] = o * (1.f / E_);
}

extern "C" void kernel_launch(void* const* d_in, const int* in_sizes, int n_in,
                              void* d_out, int out_size, void* d_ws, size_t ws_size,
                              hipStream_t stream){
  const float* z        = (const float*)d_in[0];
  const float* supports = (const float*)d_in[1];
  const float* labels   = (const float*)d_in[2];
  const float* weight   = (const float*)d_in[3];
  const float* alpha    = (const float*)d_in[4];
  const float* gamma    = (const float*)d_in[5];
  const float* bias     = (const float*)d_in[6];
  float* out = (float*)d_out;

  char* w = (char*)d_ws;
  size_t off = 0;
  auto alloc = [&](size_t bytes)->char*{
    char* p = w + off;
    off = (off + bytes + 255) & ~(size_t)255;
    return p;
  };

  // ---- all-permanent layout (~196 MB, no overlay) ----
  float* zinv = (float*)alloc((size_t)B_ * 4);
  float* sinv = (float*)alloc((size_t)N_ * 4);
  float* cnt  = (float*)alloc((size_t)C_ * 4);
  int*   y    = (int*)  alloc((size_t)N_ * 4);
  int*   idx  = (int*)  alloc((size_t)B_ * TOPK_ * 4);
  unsigned short* SZ  = (unsigned short*)alloc((size_t)MR_ * D1_ * 2);   // sh rows 0..3455, zh rows 3456..7551
  unsigned short* zl  = (unsigned short*)alloc((size_t)B_  * D1_ * 2);
  unsigned short* sl  = (unsigned short*)alloc((size_t)NP_ * D1_ * 2);
  unsigned short* wbf = (unsigned short*)alloc((size_t)NEX_ * D1_ * 2);  // alphaW + G cols
  float* WT     = (float*)alloc((size_t)D1_ * D2_ * 4);
  float* part   = (float*)alloc((size_t)8 * C_ * D1_ * 4);
  float* P      = (float*)alloc((size_t)C_ * D1_ * 4);
  float* A2     = (float*)alloc((size_t)EC_ * D1_ * 4);
  float* centp  = (float*)alloc((size_t)EC_ * D2_ * 4);
  float* cent   = (float*)alloc((size_t)EC_ * D2_ * 4);
  float* gcn    = (float*)alloc((size_t)EC_ * D2_ * 4);
  float* H      = (float*)alloc((size_t)EC_ * D1_ * 4);
  float* bconst = (float*)alloc((size_t)256 * 4);
  float* scores = (float*)alloc((size_t)B_ * N_ * 4);
  float* dots   = (float*)alloc((size_t)MR_ * NDOT_ * 4);
  float* norm2  = (float*)alloc((size_t)MR_ * E_ * 4);
  float* soft   = (float*)alloc((size_t)E_ * N_ * C_ * 4);
  float* part2  = (float*)alloc((size_t)8 * EC_ * D1_ * 4);   // split-K partials (max N=D1_)
  (void)ws_size; (void)in_sizes; (void)n_in; (void)out_size;

  unsigned short* sh = SZ;
  unsigned short* zh = SZ + (size_t)ZOFF_ * D1_;

  // row norms + label prep
  rownorm_inv<<<B_, 256, 0, stream>>>(z, D1_, zinv);
  rownorm_inv<<<N_, 256, 0, stream>>>(supports, D1_, sinv);
  zero_cnt<<<1, 32, 0, stream>>>(cnt);
  labelprep<<<(N_ + 255) / 256, 256, 0, stream>>>(labels, y, cnt);

  // zero fills: sh pad, sl pad, z pad, G pad cols, norm2
  zfill<<<(14336 + 255) / 256, 256, 0, stream>>>((uint4*)(sh + (size_t)N_ * D1_), 14336);
  zfill<<<(14336 + 255) / 256, 256, 0, stream>>>((uint4*)(sl + (size_t)N_ * D1_), 14336);
  zfill<<<(32768 + 255) / 256, 256, 0, stream>>>((uint4*)(SZ + (size_t)(ZOFF_ + B_) * D1_), 32768);
  zfill<<<(22016 + 255) / 256, 256, 0, stream>>>((uint4*)(wbf + (size_t)(NE_ + EC_) * D1_), 22016);
  zfill<<<(19200 + 255) / 256, 256, 0, stream>>>((uint4*)norm2, 19200);

  // bf16 precompute
  cvt_split<<<(B_ * D1_ / 4 + 255) / 256, 256, 0, stream>>>(z, zh, zl, (long)B_ * D1_ / 4);
  cvt_split<<<(N_ * D1_ / 4 + 255) / 256, 256, 0, stream>>>(supports, sh, sl, (long)N_ * D1_ / 4);
  wfold<<<(int)((long)NE_ * D1_ / 4 / 256), 256, 0, stream>>>(weight, alpha, wbf);
  transposeW<<<dim3(D1_ / 32, D2_ / 32), 256, 0, stream>>>(weight, WT);

  // cosine scores (2-phase 256^2, flat 3-segment K) + top-20
  sc2<<<dim3(NP2_ / 256, B_ / 256, 1), 512, 0, stream>>>(
      zh, zl, sh, sl, zinv, sinv, scores);
  topk20<<<B_, 256, 0, stream>>>(scores, idx);

  // centroid path (fp32, low-rank): P -> A2 -> centpre -> cent -> normalize -> gcn -> H -> G, bconst
  pbuild<<<dim3(D1_ / 256, 8), 256, 0, stream>>>(supports, y, cnt, part);
  preduce<<<(C_ * D1_ + 255) / 256, 256, 0, stream>>>(part, P);
  a2build<<<(EC_ * D1_ + 255) / 256, 256, 0, stream>>>(P, alpha, A2);
  gemm64k<<<dim3(D2_ / 64, 3, 8), 256, 0, stream>>>(
      A2, D1_, weight, D1_, part2, EC_, D2_, 256);
  reduceK<<<(int)(((long)EC_ * D2_ + 255) / 256), 256, 0, stream>>>(part2, centp, (long)EC_ * D2_);
  centscale<<<(EC_ * D2_ + 255) / 256, 256, 0, stream>>>(centp, gamma, bias, cnt, cent);
  rownorm_inplace<<<EC_, 256, 0, stream>>>(cent, D2_);
  gcnbuild<<<(EC_ * D2_ + 255) / 256, 256, 0, stream>>>(cent, gamma, gcn);
  gemm64k<<<dim3(D1_ / 64, 3, 8), 256, 0, stream>>>(
      gcn, D2_, WT, D2_, part2, EC_, D1_, 128);
  reduceK<<<(int)(((long)EC_ * D1_ + 255) / 256), 256, 0, stream>>>(part2, H, (long)EC_ * D1_);
  gbuild<<<(EC_ * D1_ + 255) / 256, 256, 0, stream>>>(H, alpha, wbf);
  bconst_build<<<(EC_ + 3) / 4, 256, 0, stream>>>(bias, cent, bconst);

  // fused norm+dot GEMM over all S and z rows (2-phase 256^2)
  nd2<<<dim3(NEX_ / 256, MR_ / 256, 1), 512, 0, stream>>>(
      SZ, wbf, gamma, bias, norm2, dots);

  // finalize
  soft_build<<<(N_ * E_ + 255) / 256, 256, 0, stream>>>(dots, norm2, bconst, soft);
  outputs_k<<<B_ / 4, 256, 0, stream>>>(soft, idx, out);
  logits_fin<<<(B_ * E_ + 255) / 256, 256, 0, stream>>>(dots, norm2, bconst, out);
}